// Round 11
// baseline (541.957 us; speedup 1.0000x reference)
//
#include <hip/hip_runtime.h>
#include <cstdint>
#include <cstddef>

#define B_   2
#define S_   2048
#define HID_ 4096
#define H_   32
#define KV_  8
#define D_   128
#define M_   (B_*S_)      // 4096 tokens
#define QSTR 6144         // QKV combined row stride (H*D + 2*KV*D)

typedef __attribute__((ext_vector_type(8))) short bf16x8;
typedef __attribute__((ext_vector_type(4))) float f32x4;
typedef __attribute__((ext_vector_type(16))) float f32x16;
typedef __attribute__((ext_vector_type(4))) unsigned int u32x4;
typedef unsigned short u16;
typedef unsigned int   u32;

// softmax scale folded into exp2: SCALE * log2(e)
#define KSC (0.08838834764831845f * 1.4426950408889634f)

__device__ __forceinline__ float bf2f(u16 v){ u32 u = ((u32)v) << 16; return __builtin_bit_cast(float, u); }
__device__ __forceinline__ u16 f2bf(float f){
  u32 u = __builtin_bit_cast(u32, f);
  u32 r = u + 0x7fffu + ((u >> 16) & 1u);   // RNE
  return (u16)(r >> 16);
}

__device__ __forceinline__ void gload_lds16(const void* g, void* lds){
  __builtin_amdgcn_global_load_lds(
      (const __attribute__((address_space(1))) void*)g,
      (__attribute__((address_space(3))) void*)lds, 16, 0, 0);
}

#define BAR() __builtin_amdgcn_s_barrier()

// ---------------- cast fp32 -> bf16 (vectorized) ----------------
__global__ void cast_f32_bf16(const float* __restrict__ in, u16* __restrict__ out, int n){
  int i = (blockIdx.x * blockDim.x + threadIdx.x) * 4;
  if (i >= n) return;
  float4 v = *(const float4*)(in + i);
  ushort4 o;
  o.x = f2bf(v.x); o.y = f2bf(v.y); o.z = f2bf(v.z); o.w = f2bf(v.w);
  *(ushort4*)(out + i) = o;
}

// ---------------- merged transpose-cast of all 4 weights (one launch) ----------------
__global__ __launch_bounds__(256) void tcast_all(const float* __restrict__ Wq, const float* __restrict__ Wk,
                                                 const float* __restrict__ Wv, const float* __restrict__ Wo,
                                                 u16* __restrict__ WT, u16* __restrict__ WoT){
  int bid = blockIdx.x;
  const float* W; u16* Dp; int Nd, kx, ny;
  if (bid < 4096){       W = Wq; Dp = WT;                         Nd = 4096; kx = bid & 63;        ny = bid >> 6; }
  else if (bid < 5120){  W = Wk; Dp = WT + (size_t)4096 * 4096;   Nd = 1024; kx = (bid-4096) & 63; ny = (bid-4096) >> 6; }
  else if (bid < 6144){  W = Wv; Dp = WT + (size_t)5120 * 4096;   Nd = 1024; kx = (bid-5120) & 63; ny = (bid-5120) >> 6; }
  else {                 W = Wo; Dp = WoT;                        Nd = 4096; kx = (bid-6144) & 63; ny = (bid-6144) >> 6; }
  __shared__ __align__(16) u16 t[64][65];     // t[n][k]
  int k0 = kx * 64, n0 = ny * 64;
  int lx = threadIdx.x & 15, ly = threadIdx.x >> 4;
  #pragma unroll
  for (int rr = 0; rr < 4; ++rr){
    int r = rr * 16 + ly;                     // k-row in tile
    float4 v = *(const float4*)(W + (size_t)(k0 + r) * Nd + n0 + lx * 4);
    t[lx*4+0][r] = f2bf(v.x);
    t[lx*4+1][r] = f2bf(v.y);
    t[lx*4+2][r] = f2bf(v.z);
    t[lx*4+3][r] = f2bf(v.w);
  }
  __syncthreads();
  #pragma unroll
  for (int rr = 0; rr < 4; ++rr){
    int r = rr * 16 + ly;                     // n-row in tile
    ushort4 o;
    o.x = t[r][lx*4+0]; o.y = t[r][lx*4+1]; o.z = t[r][lx*4+2]; o.w = t[r][lx*4+3];
    *(ushort4*)(Dp + (size_t)(n0 + r) * 4096 + k0 + lx * 4) = o;
  }
}

// ---------------- transpose V (bf16): QKV[t][5120 + vd] -> Vt[b*1024+vd][s] ----------------
__global__ __launch_bounds__(256) void vtrans(const u16* __restrict__ QKV, u16* __restrict__ Vt){
  __shared__ __align__(16) u16 t[64][65];
  int stile = blockIdx.x;                 // 0..31
  int b = blockIdx.y >> 4, vt = blockIdx.y & 15;
  int s0 = stile * 64, c0 = vt * 64;
  int lx = threadIdx.x & 15, ly = threadIdx.x >> 4;
  #pragma unroll
  for (int rr = 0; rr < 4; ++rr){
    int r = rr * 16 + ly;                 // s-row
    ushort4 v = *(const ushort4*)(QKV + (size_t)(b*S_ + s0 + r) * QSTR + 5120 + c0 + lx*4);
    t[lx*4+0][r]=v.x; t[lx*4+1][r]=v.y; t[lx*4+2][r]=v.z; t[lx*4+3][r]=v.w;
  }
  __syncthreads();
  #pragma unroll
  for (int rr = 0; rr < 4; ++rr){
    int r = rr * 16 + ly;                 // vd-row
    ushort4 o;
    o.x=t[r][lx*4+0]; o.y=t[r][lx*4+1]; o.z=t[r][lx*4+2]; o.w=t[r][lx*4+3];
    *(ushort4*)(Vt + (size_t)(b*1024 + c0 + r) * S_ + s0 + lx*4) = o;
  }
}

// ---------------- RoPE in-place on bf16 [M_][stride] rows (K heads only) ----------------
__global__ void rope_k(u16* __restrict__ X, const int* __restrict__ pos, int hshift, int stride){
  int idx = blockIdx.x * 256 + threadIdx.x;
  int i = idx & 63;
  int h = (idx >> 6) & ((1 << hshift) - 1);
  int t = idx >> (6 + hshift);
  u16* p0 = X + (size_t)t * stride + h * D_ + i;
  float x1 = bf2f(p0[0]), x2 = bf2f(p0[64]);
  float fpos = (float)pos[t];
  float invf = exp2f(-(float)(2 * i) * (13.287712379549449f / 128.0f));
  float f = fpos * invf;
  float sv = __sinf(f), cv = __cosf(f);
  p0[0]  = f2bf(x1 * cv - x2 * sv);
  p0[64] = f2bf(x2 * cv + x1 * sv);
}

// ============ gemm32: BM=256, BN=NB*64, BK=32, 3-slot LDS, ONE barrier per K-tile ============
// 8 waves (2M x 4N), per-wave output 128 x (NB*16). Counted vmcnt(4) (never 0 until tail).
// Slot rotation sa/sb/sc: STAGE(t+2)->sc never aliases live sa (read now) or sb (read next);
// RAW: end-of-iter-(t-1) vmcnt(4)+BAR forces tile t resident collectively before compute(t).
// WAR: sc held tile t-1, whose ds_reads were consumed before iter t-1's ending BAR.
// Chunk-XOR swizzle: LDS[row][c] = G[row][c ^ ((row>>1)&3)], read chunk lk ^ ((lr>>1)&3)
// -> 8 bank-quad groups x 8 lanes = minimal (conflict-free) for wave64 b128.
template<int NB, bool OUTF32>
__global__ __launch_bounds__(512, 2) void gemm32(const u16* __restrict__ A, const u16* __restrict__ Bt,
                                                 void* __restrict__ C, int Nn, int mt){
  constexpr int BN = NB * 64;
  constexpr int BSLOT = BN * 64;              // bytes per B slot (BN rows x 32k x 2B)
  __shared__ __align__(16) u16 smem[(49152 + 3 * BSLOT) / 2];
  const int tid = threadIdx.x, l = tid & 63, w = tid >> 6;
  const int lr = l & 15, lk = l >> 4;
  const int wr = w >> 2, wc = w & 3;

  // bijective XCD swizzle (nwg % 8 == 0 for both grids)
  const int nwg = gridDim.x;
  const int sbid = ((int)blockIdx.x & 7) * (nwg >> 3) + ((int)blockIdx.x >> 3);
  const int bx = sbid % mt, by = sbid / mt;
  const size_t arow0 = (size_t)bx * 256, bcol0 = (size_t)by * BN;
  const char* Ag = (const char*)(A + arow0 * 4096);
  const char* Bg = (const char*)(Bt + bcol0 * 4096);

  // staging sources (pre-swizzled); NB==3: threads with idx>=768 duplicate idx-256 (benign,
  // same src -> same dst) to keep loads/tile uniform at 4 for every thread.
  size_t asrc[2], bsrc[2]; int bdst[2];
  #pragma unroll
  for (int r2 = 0; r2 < 2; ++r2){
    int idx = r2 * 512 + tid;
    int row = idx >> 2, c = idx & 3;
    asrc[r2] = (size_t)row * 8192 + (size_t)((c ^ ((row >> 1) & 3)) << 4);
    int bidx = idx; if (NB == 3 && bidx >= 768) bidx -= 256;
    int brow = bidx >> 2, bc = bidx & 3;
    bsrc[r2] = (size_t)brow * 8192 + (size_t)((bc ^ ((brow >> 1) & 3)) << 4);
    bdst[r2] = bidx * 16;
  }

  const int csw  = (lk ^ ((lr >> 1) & 3)) << 3;          // u16 units
  const int aoff = (wr * 128 + lr) * 32 + csw;
  const int boff = (wc * (NB * 16) + lr) * 32 + csw;

  f32x4 acc[8][NB];
  #pragma unroll
  for (int i = 0; i < 8; ++i)
    #pragma unroll
    for (int j = 0; j < NB; ++j){ acc[i][j][0]=0.f; acc[i][j][1]=0.f; acc[i][j][2]=0.f; acc[i][j][3]=0.f; }

  auto STAGE = [&](int kt, int s){
    const size_t kb = (size_t)kt * 64;        // 32 elems = 64 B per K-tile
    gload_lds16(Ag + asrc[0] + kb, (char*)smem + s * 16384 + tid * 16);
    gload_lds16(Ag + asrc[1] + kb, (char*)smem + s * 16384 + 8192 + tid * 16);
    gload_lds16(Bg + bsrc[0] + kb, (char*)smem + 49152 + s * BSLOT + bdst[0]);
    gload_lds16(Bg + bsrc[1] + kb, (char*)smem + 49152 + s * BSLOT + bdst[1]);
  };

  STAGE(0, 0); STAGE(1, 1);
  asm volatile("s_waitcnt vmcnt(4)" ::: "memory");
  BAR();

  int sa = 0, sb = 1, sc = 2;
  for (int t = 0; t < 128; ++t){
    if (t + 2 < 128) STAGE(t + 2, sc);
    const int abase = sa * 8192 + aoff;                 // u16 units (A slot = 8192 u16)
    const int bbase = 24576 + sa * (BSLOT / 2) + boff;  // u16 units
    bf16x8 af[8], bfr[NB];
    #pragma unroll
    for (int m = 0; m < 8; ++m)  af[m]  = *(const bf16x8*)&smem[abase + m * 512];
    #pragma unroll
    for (int n = 0; n < NB; ++n) bfr[n] = *(const bf16x8*)&smem[bbase + n * 512];
    __builtin_amdgcn_s_setprio(1);
    #pragma unroll
    for (int m = 0; m < 8; ++m)
      #pragma unroll
      for (int n = 0; n < NB; ++n)
        acc[m][n] = __builtin_amdgcn_mfma_f32_16x16x32_bf16(af[m], bfr[n], acc[m][n], 0, 0, 0);
    __builtin_amdgcn_s_setprio(0);
    if (t < 126)       asm volatile("s_waitcnt vmcnt(4)" ::: "memory");
    else if (t == 126) asm volatile("s_waitcnt vmcnt(0)" ::: "memory");
    BAR();
    int s0 = sa; sa = sb; sb = sc; sc = s0;
  }

  // epilogue: row = wr*128 + m*16 + lk*4 + j; col = wc*(NB*16) + n*16 + lr  [m89 layout]
  #pragma unroll
  for (int m = 0; m < 8; ++m)
    #pragma unroll
    for (int n = 0; n < NB; ++n)
      #pragma unroll
      for (int j = 0; j < 4; ++j){
        size_t gr = arow0 + wr * 128 + m * 16 + lk * 4 + j;
        size_t gc = bcol0 + wc * (NB * 16) + n * 16 + lr;
        float v = acc[m][n][j];
        if (OUTF32) ((float*)C)[gr * Nn + gc] = v;
        else        ((u16*)C)[gr * Nn + gc] = f2bf(v);
      }
}

// ---------------- flash attention: 8 waves x 32 q-rows, KVBLK=64, 32x32x16 MFMA ----------------
// fused Q-RoPE, defer-max (T13), CU-pair-balanced qb order.
__global__ __launch_bounds__(512, 2) void attn_k(const u16* __restrict__ QKV,
                                                 const u16* __restrict__ Vtg,
                                                 const int* __restrict__ pos,
                                                 u16* __restrict__ ctx){
  __shared__ __align__(16) u16 smem[32768];   // 64 KB
  const int tid = threadIdx.x;
  const int l = tid & 63, w = tid >> 6;
  const int lane31 = l & 31, hi = l >> 5;
  const int hb = blockIdx.x;
  const int b = hb >> 5, h = hb & 31, kvh = h >> 2;
  const int y = blockIdx.y;
  const int qb = (y < 4) ? (7 - y) : (y - 4);   // pairs (7,0),(6,1),(5,2),(4,3) co-resident
  const int q0w = qb * 256 + w * 32;
  const int qg = q0w + lane31;

  const u16* Qp = QKV + (size_t)b * S_ * QSTR + (size_t)h * D_;
  const char* Kp = (const char*)(QKV + (size_t)b * S_ * QSTR + 4096 + (size_t)kvh * D_);
  const char* Vp = (const char*)(Vtg + ((size_t)b * 1024 + kvh * 128) * S_);

  bf16x8 qf[8];
  #pragma unroll
  for (int dt = 0; dt < 8; ++dt)
    qf[dt] = *(const bf16x8*)(Qp + (size_t)qg * QSTR + dt * 16 + hi * 8);

  // fused Q-RoPE: qf[dt][j] holds d = dt*16 + hi*8 + j; pairs (d, d+64) = (qf[dt], qf[dt+4])
  {
    float fp = (float)pos[b * S_ + qg];
    #pragma unroll
    for (int dt = 0; dt < 4; ++dt){
      bf16x8 lo = qf[dt], hi8 = qf[dt + 4], nlo, nhi;
      #pragma unroll
      for (int j = 0; j < 8; ++j){
        int d = dt * 16 + hi * 8 + j;
        float invf = exp2f(-(float)(2 * d) * (13.287712379549449f / 128.0f));
        float f = fp * invf;
        float sv = __sinf(f), cv = __cosf(f);
        float x1 = bf2f((u16)lo[j]), x2 = bf2f((u16)hi8[j]);
        nlo[j] = (short)f2bf(x1 * cv - x2 * sv);
        nhi[j] = (short)f2bf(x2 * cv + x1 * sv);
      }
      qf[dt] = nlo; qf[dt + 4] = nhi;
    }
  }

  const int krow0 = (2*w)*4 + (l >> 4), krow1 = krow0 + 4;
  const size_t koff0 = (size_t)krow0 * (QSTR*2) + (((l & 15) << 4) ^ ((krow0 & 7) << 4));
  const size_t koff1 = (size_t)krow1 * (QSTR*2) + (((l & 15) << 4) ^ ((krow1 & 7) << 4));
  const int vrow0 = (2*w)*8 + (l >> 3), vrow1 = vrow0 + 8;
  const size_t voff0 = (size_t)vrow0 * (S_*2) + (((l & 7) << 4) ^ ((vrow0 & 7) << 4));
  const size_t voff1 = (size_t)vrow1 * (S_*2) + (((l & 7) << 4) ^ ((vrow1 & 7) << 4));

  f32x16 acc[4];
  #pragma unroll
  for (int dt = 0; dt < 4; ++dt)
    #pragma unroll
    for (int i = 0; i < 16; ++i) acc[dt][i] = 0.f;
  float mrow = -3e38f, lsum = 0.f;

  const int nt = qb * 4 + 4;

  auto STAGE = [&](int t, int bufn){
    char* Kb = (char*)smem + bufn * 16384;
    char* Vb = (char*)smem + 32768 + bufn * 16384;
    size_t kb = (size_t)t * 64 * (QSTR*2);
    size_t vb = (size_t)t * 128;
    gload_lds16(Kp + kb + koff0, Kb + (2*w)*1024);
    gload_lds16(Kp + kb + koff1, Kb + (2*w+1)*1024);
    gload_lds16(Vp + vb + voff0, Vb + (2*w)*1024);
    gload_lds16(Vp + vb + voff1, Vb + (2*w+1)*1024);
  };

  STAGE(0, 0);
  __syncthreads();
  int buf = 0;
  for (int t = 0; t < nt; ++t){
    if (t + 1 < nt) STAGE(t + 1, buf ^ 1);
    const int kbase = t * 64;
    if (kbase <= q0w + 31){
      const char* Kb = (const char*)smem + buf * 16384;
      const char* Vb = (const char*)smem + 32768 + buf * 16384;
      const int swz = (lane31 & 7) << 4;

      f32x16 s0, s1;
      #pragma unroll
      for (int i = 0; i < 16; ++i){ s0[i] = 0.f; s1[i] = 0.f; }
      #pragma unroll
      for (int dt = 0; dt < 8; ++dt){
        bf16x8 kf = *(const bf16x8*)(Kb + lane31*256 + ((dt*32 + hi*16) ^ swz));
        s0 = __builtin_amdgcn_mfma_f32_32x32x16_bf16(kf, qf[dt], s0, 0, 0, 0);
      }
      #pragma unroll
      for (int dt = 0; dt < 8; ++dt){
        bf16x8 kf = *(const bf16x8*)(Kb + (32 + lane31)*256 + ((dt*32 + hi*16) ^ swz));
        s1 = __builtin_amdgcn_mfma_f32_32x32x16_bf16(kf, qf[dt], s1, 0, 0, 0);
      }

      if (kbase + 63 > q0w){
        int thr = qg - kbase;
        #pragma unroll
        for (int r = 0; r < 16; ++r){
          int kc = (r & 3) + 8*(r >> 2) + 4*hi;
          s0[r] = (kc > thr)      ? -1e30f : s0[r];
          s1[r] = (kc + 32 > thr) ? -1e30f : s1[r];
        }
      }

      float tmax = s0[0];
      #pragma unroll
      for (int r = 1; r < 16; ++r) tmax = fmaxf(tmax, s0[r]);
      #pragma unroll
      for (int r = 0; r < 16; ++r) tmax = fmaxf(tmax, s1[r]);
      tmax = fmaxf(tmax, __shfl_xor(tmax, 32));
      // defer-max (T13): skip O-rescale while growth <= 8 exp2-bits (62.7 raw)
      if (!__all(tmax - mrow <= 62.7f)){
        float mn = fmaxf(mrow, tmax);
        float rf = exp2f((mrow - mn) * KSC);
        mrow = mn;
        lsum *= rf;
        #pragma unroll
        for (int dt = 0; dt < 4; ++dt)
          #pragma unroll
          for (int i = 0; i < 16; ++i) acc[dt][i] *= rf;
      }
      float ps = 0.f;
      #pragma unroll
      for (int r = 0; r < 16; ++r){
        float a = exp2f((s0[r] - mrow) * KSC);
        float c = exp2f((s1[r] - mrow) * KSC);
        s0[r] = a; s1[r] = c; ps += a + c;
      }
      ps += __shfl_xor(ps, 32);
      lsum += ps;

      u32 pw[16];
      #pragma unroll
      for (int g = 0; g < 4; ++g){
        pw[2*g]     = (u32)f2bf(s0[4*g])   | ((u32)f2bf(s0[4*g+1]) << 16);
        pw[2*g+1]   = (u32)f2bf(s0[4*g+2]) | ((u32)f2bf(s0[4*g+3]) << 16);
        pw[8+2*g]   = (u32)f2bf(s1[4*g])   | ((u32)f2bf(s1[4*g+1]) << 16);
        pw[8+2*g+1] = (u32)f2bf(s1[4*g+2]) | ((u32)f2bf(s1[4*g+3]) << 16);
      }

      #pragma unroll
      for (int kt = 0; kt < 4; ++kt){
        u32 W0 = pw[kt*4+0], W1 = pw[kt*4+1], W2 = pw[kt*4+2], W3 = pw[kt*4+3];
        u32 x0 = hi ? W0 : W2;
        u32 x1 = hi ? W1 : W3;
        u32 y0 = __shfl_xor(x0, 32);
        u32 y1 = __shfl_xor(x1, 32);
        u32 w0 = hi ? y0 : W0;
        u32 w1 = hi ? y1 : W1;
        u32 w2 = hi ? W2 : y0;
        u32 w3 = hi ? W3 : y1;
        u32x4 pk; pk[0]=w0; pk[1]=w1; pk[2]=w2; pk[3]=w3;
        bf16x8 pa = __builtin_bit_cast(bf16x8, pk);
        #pragma unroll
        for (int dt = 0; dt < 4; ++dt){
          bf16x8 vf = *(const bf16x8*)(Vb + (dt*32 + lane31)*128 + ((kt*32 + hi*16) ^ swz));
          acc[dt] = __builtin_amdgcn_mfma_f32_32x32x16_bf16(vf, pa, acc[dt], 0, 0, 0);
        }
      }
    }
    __syncthreads();
    buf ^= 1;
  }

  __syncthreads();
  u16* Ot = smem + w * 4096;
  float inv = 1.f / lsum;
  #pragma unroll
  for (int dt = 0; dt < 4; ++dt)
    #pragma unroll
    for (int r = 0; r < 16; ++r){
      int d = dt*32 + (r & 3) + 8*(r >> 2) + 4*hi;
      Ot[lane31*128 + (d ^ ((lane31 & 15) << 2))] = f2bf(acc[dt][r] * inv);
    }
  u16* outp = ctx + ((size_t)(b * S_ + q0w)) * HID_ + h * D_;
  #pragma unroll
  for (int it = 0; it < 16; ++it){
    int id = it * 64 + l;
    int q = id >> 5;
    int c4 = (id & 31) * 4;
    ushort4 vv = *(const ushort4*)(Ot + q*128 + (c4 ^ ((q & 15) << 2)));
    *(ushort4*)(outp + (size_t)q * HID_ + c4) = vv;
  }
}

extern "C" void kernel_launch(void* const* d_in, const int* in_sizes, int n_in,
                              void* d_out, int out_size, void* d_ws, size_t ws_size,
                              hipStream_t stream) {
  const float* x  = (const float*)d_in[0];
  const int*   pos = (const int*)d_in[2];
  const float* Wq = (const float*)d_in[3];
  const float* Wk = (const float*)d_in[4];
  const float* Wv = (const float*)d_in[5];
  const float* Wo = (const float*)d_in[6];

  char* ws = (char*)d_ws;
  u16* xb   = (u16*)(ws);                               // 32MB; reused as ctx after QKV
  u16* WT   = (u16*)(ws + ((size_t)32 << 20));          // 48MB: Wq^T|Wk^T|Wv^T (dead after QKV gemm)
  u16* WoT  = (u16*)(ws + ((size_t)80 << 20));          // 32MB
  u16* QKVb = (u16*)(ws + ((size_t)112 << 20));         // 48MB: [4096][6144]
  u16* Vtg  = (u16*)(ws + ((size_t)32 << 20));          // 8MB overlay on WT: [b*1024+vd][S]

  cast_f32_bf16<<<16384, 256, 0, stream>>>(x, xb, HID_ * M_);
  tcast_all<<<10240, 256, 0, stream>>>(Wq, Wk, Wv, Wo, WT, WoT);
  gemm32<3, false><<<512, 512, 0, stream>>>(xb, WT, QKVb, 6144, 16);
  rope_k<<<8192, 256, 0, stream>>>(QKVb + 4096, pos, 3, QSTR);   // K heads only; Q-RoPE fused in attn
  vtrans<<<dim3(32, 32), 256, 0, stream>>>(QKVb, Vtg);
  attn_k<<<dim3(64, 8), 512, 0, stream>>>(QKVb, Vtg, pos, xb);
  gemm32<4, true><<<256, 512, 0, stream>>>(xb, WoT, d_out, 4096, 16);
}

// Round 12
// 515.624 us; speedup vs baseline: 1.0511x; 1.0511x over previous
//
#include <hip/hip_runtime.h>
#include <cstdint>
#include <cstddef>

#define B_   2
#define S_   2048
#define HID_ 4096
#define H_   32
#define KV_  8
#define D_   128
#define M_   (B_*S_)      // 4096 tokens
#define QSTR 6144         // QKV combined row stride (H*D + 2*KV*D)

typedef __attribute__((ext_vector_type(8))) short bf16x8;
typedef __attribute__((ext_vector_type(4))) float f32x4;
typedef __attribute__((ext_vector_type(16))) float f32x16;
typedef __attribute__((ext_vector_type(4))) unsigned int u32x4;
typedef unsigned short u16;
typedef unsigned int   u32;

// softmax scale folded into exp2: SCALE * log2(e)
#define KSC (0.08838834764831845f * 1.4426950408889634f)

__device__ __forceinline__ float bf2f(u16 v){ u32 u = ((u32)v) << 16; return __builtin_bit_cast(float, u); }
__device__ __forceinline__ u16 f2bf(float f){
  u32 u = __builtin_bit_cast(u32, f);
  u32 r = u + 0x7fffu + ((u >> 16) & 1u);   // RNE
  return (u16)(r >> 16);
}

__device__ __forceinline__ void gload_lds16(const void* g, void* lds){
  __builtin_amdgcn_global_load_lds(
      (const __attribute__((address_space(1))) void*)g,
      (__attribute__((address_space(3))) void*)lds, 16, 0, 0);
}

#define BAR() __builtin_amdgcn_s_barrier()

// ---------------- cast fp32 -> bf16 (vectorized) ----------------
__global__ void cast_f32_bf16(const float* __restrict__ in, u16* __restrict__ out, int n){
  int i = (blockIdx.x * blockDim.x + threadIdx.x) * 4;
  if (i >= n) return;
  float4 v = *(const float4*)(in + i);
  ushort4 o;
  o.x = f2bf(v.x); o.y = f2bf(v.y); o.z = f2bf(v.z); o.w = f2bf(v.w);
  *(ushort4*)(out + i) = o;
}

// ---------------- merged transpose-cast of all 4 weights (one launch) ----------------
__global__ __launch_bounds__(256) void tcast_all(const float* __restrict__ Wq, const float* __restrict__ Wk,
                                                 const float* __restrict__ Wv, const float* __restrict__ Wo,
                                                 u16* __restrict__ WT, u16* __restrict__ WoT){
  int bid = blockIdx.x;
  const float* W; u16* Dp; int Nd, kx, ny;
  if (bid < 4096){       W = Wq; Dp = WT;                         Nd = 4096; kx = bid & 63;        ny = bid >> 6; }
  else if (bid < 5120){  W = Wk; Dp = WT + (size_t)4096 * 4096;   Nd = 1024; kx = (bid-4096) & 63; ny = (bid-4096) >> 6; }
  else if (bid < 6144){  W = Wv; Dp = WT + (size_t)5120 * 4096;   Nd = 1024; kx = (bid-5120) & 63; ny = (bid-5120) >> 6; }
  else {                 W = Wo; Dp = WoT;                        Nd = 4096; kx = (bid-6144) & 63; ny = (bid-6144) >> 6; }
  __shared__ __align__(16) u16 t[64][65];     // t[n][k]
  int k0 = kx * 64, n0 = ny * 64;
  int lx = threadIdx.x & 15, ly = threadIdx.x >> 4;
  #pragma unroll
  for (int rr = 0; rr < 4; ++rr){
    int r = rr * 16 + ly;                     // k-row in tile
    float4 v = *(const float4*)(W + (size_t)(k0 + r) * Nd + n0 + lx * 4);
    t[lx*4+0][r] = f2bf(v.x);
    t[lx*4+1][r] = f2bf(v.y);
    t[lx*4+2][r] = f2bf(v.z);
    t[lx*4+3][r] = f2bf(v.w);
  }
  __syncthreads();
  #pragma unroll
  for (int rr = 0; rr < 4; ++rr){
    int r = rr * 16 + ly;                     // n-row in tile
    ushort4 o;
    o.x = t[r][lx*4+0]; o.y = t[r][lx*4+1]; o.z = t[r][lx*4+2]; o.w = t[r][lx*4+3];
    *(ushort4*)(Dp + (size_t)(n0 + r) * 4096 + k0 + lx * 4) = o;
  }
}

// ---------------- transpose V (bf16): QKV[t][5120 + vd] -> Vt[b*1024+vd][s] ----------------
__global__ __launch_bounds__(256) void vtrans(const u16* __restrict__ QKV, u16* __restrict__ Vt){
  __shared__ __align__(16) u16 t[64][65];
  int stile = blockIdx.x;                 // 0..31
  int b = blockIdx.y >> 4, vt = blockIdx.y & 15;
  int s0 = stile * 64, c0 = vt * 64;
  int lx = threadIdx.x & 15, ly = threadIdx.x >> 4;
  #pragma unroll
  for (int rr = 0; rr < 4; ++rr){
    int r = rr * 16 + ly;                 // s-row
    ushort4 v = *(const ushort4*)(QKV + (size_t)(b*S_ + s0 + r) * QSTR + 5120 + c0 + lx*4);
    t[lx*4+0][r]=v.x; t[lx*4+1][r]=v.y; t[lx*4+2][r]=v.z; t[lx*4+3][r]=v.w;
  }
  __syncthreads();
  #pragma unroll
  for (int rr = 0; rr < 4; ++rr){
    int r = rr * 16 + ly;                 // vd-row
    ushort4 o;
    o.x=t[r][lx*4+0]; o.y=t[r][lx*4+1]; o.z=t[r][lx*4+2]; o.w=t[r][lx*4+3];
    *(ushort4*)(Vt + (size_t)(b*1024 + c0 + r) * S_ + s0 + lx*4) = o;
  }
}

// ---------------- RoPE in-place on bf16 [M_][stride] rows (K heads only) ----------------
__global__ void rope_k(u16* __restrict__ X, const int* __restrict__ pos, int hshift, int stride){
  int idx = blockIdx.x * 256 + threadIdx.x;
  int i = idx & 63;
  int h = (idx >> 6) & ((1 << hshift) - 1);
  int t = idx >> (6 + hshift);
  u16* p0 = X + (size_t)t * stride + h * D_ + i;
  float x1 = bf2f(p0[0]), x2 = bf2f(p0[64]);
  float fpos = (float)pos[t];
  float invf = exp2f(-(float)(2 * i) * (13.287712379549449f / 128.0f));
  float f = fpos * invf;
  float sv = __sinf(f), cv = __cosf(f);
  p0[0]  = f2bf(x1 * cv - x2 * sv);
  p0[64] = f2bf(x2 * cv + x1 * sv);
}

// ============ gemm256 (R8 proven): BM=BN=256, BK=64, rolled loop, no spill ============
#define STG_A(PB, HALF, KT) do{ \
  gload_lds16(Ag + off0 + (size_t)(HALF)*1048576 + (size_t)(KT)*128, \
              (char*)smem + (PB)*32768 + (HALF)*16384 + w*1024); \
  gload_lds16(Ag + off0 + 524288 + (size_t)(HALF)*1048576 + (size_t)(KT)*128, \
              (char*)smem + (PB)*32768 + (HALF)*16384 + 8192 + w*1024); }while(0)
#define STG_B(PB, HALF, KT) do{ \
  gload_lds16(Bg + off0 + (size_t)(HALF)*1048576 + (size_t)(KT)*128, \
              (char*)smem + 65536 + (PB)*32768 + (HALF)*16384 + w*1024); \
  gload_lds16(Bg + off0 + 524288 + (size_t)(HALF)*1048576 + (size_t)(KT)*128, \
              (char*)smem + 65536 + (PB)*32768 + (HALF)*16384 + 8192 + w*1024); }while(0)

#define RD_A(DST, PP, HALF) do{ \
  _Pragma("unroll") for (int ks = 0; ks < 2; ++ks) \
  _Pragma("unroll") for (int m = 0; m < 4; ++m) \
    DST[ks][m] = *(const bf16x8*)&smem[(PP)*16384 + (HALF)*8192 + aRowBase + m*1024 + csw[ks]]; }while(0)
#define RD_B(DST, PP, HALF) do{ \
  _Pragma("unroll") for (int ks = 0; ks < 2; ++ks) \
  _Pragma("unroll") for (int n = 0; n < 2; ++n) \
    DST[ks][n] = *(const bf16x8*)&smem[32768 + (PP)*16384 + (HALF)*8192 + bRowBase + n*1024 + csw[ks]]; }while(0)

template<int MO, int NO>
__device__ __forceinline__ void mfma_quad(f32x4 (&acc)[8][4],
                                          const bf16x8 (&af)[2][4], const bf16x8 (&bf)[2][2]){
  __builtin_amdgcn_s_setprio(1);
  #pragma unroll
  for (int ks = 0; ks < 2; ++ks)
    #pragma unroll
    for (int m = 0; m < 4; ++m)
      #pragma unroll
      for (int n = 0; n < 2; ++n)
        acc[MO+m][NO+n] = __builtin_amdgcn_mfma_f32_16x16x32_bf16(af[ks][m], bf[ks][n], acc[MO+m][NO+n], 0, 0, 0);
  __builtin_amdgcn_s_setprio(0);
}

template<bool OUTF32>
__global__ __launch_bounds__(512, 2) void gemm256(const u16* __restrict__ A, const u16* __restrict__ Bt,
                                                  void* __restrict__ C, int Nn, int mt){
  __shared__ __align__(16) u16 smem[65536];   // 128 KB
  const int tid = threadIdx.x;
  const int l = tid & 63, w = tid >> 6;
  const int lr = l & 15, lk = l >> 4;
  const int wr = w >> 2, wc = w & 3;

  const int nwg = gridDim.x;
  const int sbid = ((int)blockIdx.x & 7) * (nwg >> 3) + ((int)blockIdx.x >> 3);
  const int bx = sbid % mt, by = sbid / mt;
  const size_t arow0 = (size_t)bx * 256;
  const size_t brow0 = (size_t)by * 256;
  const char* Ag = (const char*)(A + arow0 * 4096);
  const char* Bg = (const char*)(Bt + brow0 * 4096);

  const size_t off0 = (size_t)(w * 8 + (l >> 3)) * 8192 + (size_t)(((l & 7) ^ (l >> 3)) << 4);

  const int aRowBase = (wr*64 + lr) * 64;
  const int bRowBase = (wc*32 + lr) * 64;
  int csw[2];
  csw[0] = ((lk     ) ^ (lr & 7)) << 3;
  csw[1] = ((lk + 4) ^ (lr & 7)) << 3;

  f32x4 acc[8][4];
  #pragma unroll
  for (int i = 0; i < 8; ++i)
    #pragma unroll
    for (int j = 0; j < 4; ++j){ acc[i][j][0]=0.f; acc[i][j][1]=0.f; acc[i][j][2]=0.f; acc[i][j][3]=0.f; }

  STG_A(0, 0, 0); STG_B(0, 0, 0); STG_A(0, 1, 0); STG_B(0, 1, 0);
  STG_A(1, 0, 1); STG_B(1, 0, 1); STG_A(1, 1, 1); STG_B(1, 1, 1);
  asm volatile("s_waitcnt vmcnt(8)" ::: "memory");
  BAR();
  bf16x8 a0c[2][4], b0c[2][2], a1f[2][4], b1f[2][2];
  RD_A(a0c, 0, 0); RD_B(b0c, 0, 0);

  for (int t = 0; t < 64; ++t){
    const int P = t & 1;
    RD_A(a1f, P, 1);
    BAR();
    mfma_quad<0,0>(acc, a0c, b0c);
    BAR();
    if (t < 62){ STG_A(P, 0, t+2); STG_B(P, 0, t+2); }
    RD_B(b1f, P, 1);
    BAR();
    mfma_quad<4,0>(acc, a1f, b0c);
    BAR();
    if (t < 62){
      STG_A(P, 1, t+2);
      asm volatile("s_waitcnt vmcnt(6)" ::: "memory");
    } else if (t == 62){
      asm volatile("s_waitcnt vmcnt(0)" ::: "memory");
    }
    BAR();
    mfma_quad<4,2>(acc, a1f, b1f);
    BAR();
    if (t < 62){ STG_B(P, 1, t+2); }
    BAR();
    mfma_quad<0,2>(acc, a0c, b1f);
    if (t < 63){ RD_A(a0c, P^1, 0); RD_B(b0c, P^1, 0); }
    BAR();
  }

  #pragma unroll
  for (int mh = 0; mh < 2; ++mh)
    #pragma unroll
    for (int m = 0; m < 4; ++m)
      #pragma unroll
      for (int nh = 0; nh < 2; ++nh)
        #pragma unroll
        for (int n = 0; n < 2; ++n)
          #pragma unroll
          for (int j = 0; j < 4; ++j){
            size_t gr = arow0 + mh*128 + wr*64 + m*16 + lk*4 + j;
            size_t gc = brow0 + nh*128 + wc*32 + n*16 + lr;
            float v = acc[mh*4+m][nh*2+n][j];
            if (OUTF32) ((float*)C)[gr * Nn + gc] = v;
            else        ((u16*)C)[gr * Nn + gc] = f2bf(v);
          }
}

// ============ gemm192 (R8 proven, 45% MfmaUtil): BM=256, BN=192, BK=64, rolled ============
#define STG_B3(PB, KT) do{ \
  _Pragma("unroll") for (int r2 = 0; r2 < 3; ++r2) \
    gload_lds16(Bg + bsrc3[r2] + (size_t)(KT)*128, \
                (char*)smem + 65536 + (PB)*24576 + r2*8192 + w*1024); }while(0)

#define RD_B0(DST, PP) do{ \
  _Pragma("unroll") for (int ks = 0; ks < 2; ++ks) \
  _Pragma("unroll") for (int n = 0; n < 2; ++n) \
    DST[ks][n] = *(const bf16x8*)&smem[32768 + (PP)*12288 + bRowBase + n*1024 + csw[ks]]; }while(0)
#define RD_B1(DST, PP) do{ \
  _Pragma("unroll") for (int ks = 0; ks < 2; ++ks) \
    DST[ks] = *(const bf16x8*)&smem[32768 + (PP)*12288 + bRowBase + 2048 + csw[ks]]; }while(0)

__device__ __forceinline__ void mfma_pair16(f32x4 (&acc)[8][3], int MO,
                                            const bf16x8 (&af)[2][4], const bf16x8 (&bf)[2][2]){
  __builtin_amdgcn_s_setprio(1);
  #pragma unroll
  for (int ks = 0; ks < 2; ++ks)
    #pragma unroll
    for (int m = 0; m < 4; ++m)
      #pragma unroll
      for (int n = 0; n < 2; ++n)
        acc[MO+m][n] = __builtin_amdgcn_mfma_f32_16x16x32_bf16(af[ks][m], bf[ks][n], acc[MO+m][n], 0, 0, 0);
  __builtin_amdgcn_s_setprio(0);
}
__device__ __forceinline__ void mfma_pair8(f32x4 (&acc)[8][3], int MO,
                                           const bf16x8 (&af)[2][4], const bf16x8 (&bf)[2]){
  __builtin_amdgcn_s_setprio(1);
  #pragma unroll
  for (int ks = 0; ks < 2; ++ks)
    #pragma unroll
    for (int m = 0; m < 4; ++m)
      acc[MO+m][2] = __builtin_amdgcn_mfma_f32_16x16x32_bf16(af[ks][m], bf[ks], acc[MO+m][2], 0, 0, 0);
  __builtin_amdgcn_s_setprio(0);
}

__global__ __launch_bounds__(512, 2) void gemm192(const u16* __restrict__ A, const u16* __restrict__ Bt,
                                                  u16* __restrict__ C, int Nn, int mt){
  __shared__ __align__(16) u16 smem[57344];   // 112 KB
  const int tid = threadIdx.x;
  const int l = tid & 63, w = tid >> 6;
  const int lr = l & 15, lk = l >> 4;
  const int wr = w >> 2, wc = w & 3;

  const int nwg = gridDim.x;
  const int sbid = ((int)blockIdx.x & 7) * (nwg >> 3) + ((int)blockIdx.x >> 3);
  const int bx = sbid % mt, by = sbid / mt;
  const size_t arow0 = (size_t)bx * 256;
  const size_t bcol0 = (size_t)by * 192;
  const char* Ag = (const char*)(A + arow0 * 4096);
  const char* Bg = (const char*)(Bt + bcol0 * 4096);

  const size_t off0 = (size_t)(w * 8 + (l >> 3)) * 8192 + (size_t)(((l & 7) ^ (l >> 3)) << 4);
  size_t bsrc3[3];
  #pragma unroll
  for (int r2 = 0; r2 < 3; ++r2){
    int idx = r2 * 512 + tid;
    int row = idx >> 3, ch = idx & 7;
    bsrc3[r2] = (size_t)row * 8192 + (size_t)((ch ^ (row & 7)) << 4);
  }

  const int aRowBase = (wr*64 + lr) * 64;
  const int bRowBase = (wc*48 + lr) * 64;
  int csw[2];
  csw[0] = ((lk     ) ^ (lr & 7)) << 3;
  csw[1] = ((lk + 4) ^ (lr & 7)) << 3;

  f32x4 acc[8][3];
  #pragma unroll
  for (int i = 0; i < 8; ++i)
    #pragma unroll
    for (int j = 0; j < 3; ++j){ acc[i][j][0]=0.f; acc[i][j][1]=0.f; acc[i][j][2]=0.f; acc[i][j][3]=0.f; }

  STG_A(0, 0, 0); STG_A(0, 1, 0); STG_B3(0, 0);
  STG_A(1, 0, 1); STG_A(1, 1, 1); STG_B3(1, 1);
  asm volatile("s_waitcnt vmcnt(7)" ::: "memory");
  BAR();
  bf16x8 a0c[2][4], a1f[2][4], b0c[2][2], b1f[2];
  RD_A(a0c, 0, 0); RD_B0(b0c, 0);

  for (int t = 0; t < 64; ++t){
    const int P = t & 1;
    RD_A(a1f, P, 1);
    BAR();
    mfma_pair16(acc, 0, a0c, b0c);
    BAR();
    if (t < 62){ STG_A(P, 0, t+2); }
    RD_B1(b1f, P);
    BAR();
    mfma_pair16(acc, 4, a1f, b0c);
    BAR();
    if (t < 62){
      STG_A(P, 1, t+2);
      asm volatile("s_waitcnt vmcnt(4)" ::: "memory");
    } else if (t == 62){
      asm volatile("s_waitcnt vmcnt(0)" ::: "memory");
    }
    BAR();
    mfma_pair8(acc, 4, a1f, b1f);
    BAR();
    if (t < 62){ STG_B3(P, t+2); }
    BAR();
    mfma_pair8(acc, 0, a0c, b1f);
    if (t < 63){ RD_A(a0c, P^1, 0); RD_B0(b0c, P^1); }
    BAR();
  }

  #pragma unroll
  for (int mh = 0; mh < 2; ++mh)
    #pragma unroll
    for (int m = 0; m < 4; ++m)
      #pragma unroll
      for (int f = 0; f < 3; ++f)
        #pragma unroll
        for (int j = 0; j < 4; ++j){
          size_t gr = arow0 + mh*128 + wr*64 + m*16 + lk*4 + j;
          size_t gc = bcol0 + wc*48 + f*16 + lr;
          C[gr * Nn + gc] = f2bf(acc[mh*4+m][f][j]);
        }
}

// ---------------- flash attention: 8 waves x 32 q-rows, KVBLK=64, 32x32x16 MFMA ----------------
// fused Q-RoPE, defer-max (T13), CU-pair-balanced qb order, setprio around MFMA clusters (T5).
__global__ __launch_bounds__(512, 2) void attn_k(const u16* __restrict__ QKV,
                                                 const u16* __restrict__ Vtg,
                                                 const int* __restrict__ pos,
                                                 u16* __restrict__ ctx){
  __shared__ __align__(16) u16 smem[32768];   // 64 KB
  const int tid = threadIdx.x;
  const int l = tid & 63, w = tid >> 6;
  const int lane31 = l & 31, hi = l >> 5;
  const int hb = blockIdx.x;
  const int b = hb >> 5, h = hb & 31, kvh = h >> 2;
  const int y = blockIdx.y;
  const int qb = (y < 4) ? (7 - y) : (y - 4);   // pairs (7,0),(6,1),(5,2),(4,3) co-resident
  const int q0w = qb * 256 + w * 32;
  const int qg = q0w + lane31;

  const u16* Qp = QKV + (size_t)b * S_ * QSTR + (size_t)h * D_;
  const char* Kp = (const char*)(QKV + (size_t)b * S_ * QSTR + 4096 + (size_t)kvh * D_);
  const char* Vp = (const char*)(Vtg + ((size_t)b * 1024 + kvh * 128) * S_);

  bf16x8 qf[8];
  #pragma unroll
  for (int dt = 0; dt < 8; ++dt)
    qf[dt] = *(const bf16x8*)(Qp + (size_t)qg * QSTR + dt * 16 + hi * 8);

  // fused Q-RoPE: qf[dt][j] holds d = dt*16 + hi*8 + j; pairs (d, d+64) = (qf[dt], qf[dt+4])
  {
    float fp = (float)pos[b * S_ + qg];
    #pragma unroll
    for (int dt = 0; dt < 4; ++dt){
      bf16x8 lo = qf[dt], hi8 = qf[dt + 4], nlo, nhi;
      #pragma unroll
      for (int j = 0; j < 8; ++j){
        int d = dt * 16 + hi * 8 + j;
        float invf = exp2f(-(float)(2 * d) * (13.287712379549449f / 128.0f));
        float f = fp * invf;
        float sv = __sinf(f), cv = __cosf(f);
        float x1 = bf2f((u16)lo[j]), x2 = bf2f((u16)hi8[j]);
        nlo[j] = (short)f2bf(x1 * cv - x2 * sv);
        nhi[j] = (short)f2bf(x2 * cv + x1 * sv);
      }
      qf[dt] = nlo; qf[dt + 4] = nhi;
    }
  }

  const int krow0 = (2*w)*4 + (l >> 4), krow1 = krow0 + 4;
  const size_t koff0 = (size_t)krow0 * (QSTR*2) + (((l & 15) << 4) ^ ((krow0 & 7) << 4));
  const size_t koff1 = (size_t)krow1 * (QSTR*2) + (((l & 15) << 4) ^ ((krow1 & 7) << 4));
  const int vrow0 = (2*w)*8 + (l >> 3), vrow1 = vrow0 + 8;
  const size_t voff0 = (size_t)vrow0 * (S_*2) + (((l & 7) << 4) ^ ((vrow0 & 7) << 4));
  const size_t voff1 = (size_t)vrow1 * (S_*2) + (((l & 7) << 4) ^ ((vrow1 & 7) << 4));

  f32x16 acc[4];
  #pragma unroll
  for (int dt = 0; dt < 4; ++dt)
    #pragma unroll
    for (int i = 0; i < 16; ++i) acc[dt][i] = 0.f;
  float mrow = -3e38f, lsum = 0.f;

  const int nt = qb * 4 + 4;

  auto STAGE = [&](int t, int bufn){
    char* Kb = (char*)smem + bufn * 16384;
    char* Vb = (char*)smem + 32768 + bufn * 16384;
    size_t kb = (size_t)t * 64 * (QSTR*2);
    size_t vb = (size_t)t * 128;
    gload_lds16(Kp + kb + koff0, Kb + (2*w)*1024);
    gload_lds16(Kp + kb + koff1, Kb + (2*w+1)*1024);
    gload_lds16(Vp + vb + voff0, Vb + (2*w)*1024);
    gload_lds16(Vp + vb + voff1, Vb + (2*w+1)*1024);
  };

  STAGE(0, 0);
  __syncthreads();
  int buf = 0;
  for (int t = 0; t < nt; ++t){
    if (t + 1 < nt) STAGE(t + 1, buf ^ 1);
    const int kbase = t * 64;
    if (kbase <= q0w + 31){
      const char* Kb = (const char*)smem + buf * 16384;
      const char* Vb = (const char*)smem + 32768 + buf * 16384;
      const int swz = (lane31 & 7) << 4;

      f32x16 s0, s1;
      #pragma unroll
      for (int i = 0; i < 16; ++i){ s0[i] = 0.f; s1[i] = 0.f; }
      __builtin_amdgcn_s_setprio(1);
      #pragma unroll
      for (int dt = 0; dt < 8; ++dt){
        bf16x8 kf = *(const bf16x8*)(Kb + lane31*256 + ((dt*32 + hi*16) ^ swz));
        s0 = __builtin_amdgcn_mfma_f32_32x32x16_bf16(kf, qf[dt], s0, 0, 0, 0);
      }
      #pragma unroll
      for (int dt = 0; dt < 8; ++dt){
        bf16x8 kf = *(const bf16x8*)(Kb + (32 + lane31)*256 + ((dt*32 + hi*16) ^ swz));
        s1 = __builtin_amdgcn_mfma_f32_32x32x16_bf16(kf, qf[dt], s1, 0, 0, 0);
      }
      __builtin_amdgcn_s_setprio(0);

      if (kbase + 63 > q0w){
        int thr = qg - kbase;
        #pragma unroll
        for (int r = 0; r < 16; ++r){
          int kc = (r & 3) + 8*(r >> 2) + 4*hi;
          s0[r] = (kc > thr)      ? -1e30f : s0[r];
          s1[r] = (kc + 32 > thr) ? -1e30f : s1[r];
        }
      }

      float tmax = s0[0];
      #pragma unroll
      for (int r = 1; r < 16; ++r) tmax = fmaxf(tmax, s0[r]);
      #pragma unroll
      for (int r = 0; r < 16; ++r) tmax = fmaxf(tmax, s1[r]);
      tmax = fmaxf(tmax, __shfl_xor(tmax, 32));
      // defer-max (T13): skip O-rescale while growth <= 8 exp2-bits (62.7 raw)
      if (!__all(tmax - mrow <= 62.7f)){
        float mn = fmaxf(mrow, tmax);
        float rf = exp2f((mrow - mn) * KSC);
        mrow = mn;
        lsum *= rf;
        #pragma unroll
        for (int dt = 0; dt < 4; ++dt)
          #pragma unroll
          for (int i = 0; i < 16; ++i) acc[dt][i] *= rf;
      }
      float ps = 0.f;
      #pragma unroll
      for (int r = 0; r < 16; ++r){
        float a = exp2f((s0[r] - mrow) * KSC);
        float c = exp2f((s1[r] - mrow) * KSC);
        s0[r] = a; s1[r] = c; ps += a + c;
      }
      ps += __shfl_xor(ps, 32);
      lsum += ps;

      u32 pw[16];
      #pragma unroll
      for (int g = 0; g < 4; ++g){
        pw[2*g]     = (u32)f2bf(s0[4*g])   | ((u32)f2bf(s0[4*g+1]) << 16);
        pw[2*g+1]   = (u32)f2bf(s0[4*g+2]) | ((u32)f2bf(s0[4*g+3]) << 16);
        pw[8+2*g]   = (u32)f2bf(s1[4*g])   | ((u32)f2bf(s1[4*g+1]) << 16);
        pw[8+2*g+1] = (u32)f2bf(s1[4*g+2]) | ((u32)f2bf(s1[4*g+3]) << 16);
      }

      #pragma unroll
      for (int kt = 0; kt < 4; ++kt){
        u32 W0 = pw[kt*4+0], W1 = pw[kt*4+1], W2 = pw[kt*4+2], W3 = pw[kt*4+3];
        u32 x0 = hi ? W0 : W2;
        u32 x1 = hi ? W1 : W3;
        u32 y0 = __shfl_xor(x0, 32);
        u32 y1 = __shfl_xor(x1, 32);
        u32 w0 = hi ? y0 : W0;
        u32 w1 = hi ? y1 : W1;
        u32 w2 = hi ? W2 : y0;
        u32 w3 = hi ? W3 : y1;
        u32x4 pk; pk[0]=w0; pk[1]=w1; pk[2]=w2; pk[3]=w3;
        bf16x8 pa = __builtin_bit_cast(bf16x8, pk);
        __builtin_amdgcn_s_setprio(1);
        #pragma unroll
        for (int dt = 0; dt < 4; ++dt){
          bf16x8 vf = *(const bf16x8*)(Vb + (dt*32 + lane31)*128 + ((kt*32 + hi*16) ^ swz));
          acc[dt] = __builtin_amdgcn_mfma_f32_32x32x16_bf16(vf, pa, acc[dt], 0, 0, 0);
        }
        __builtin_amdgcn_s_setprio(0);
      }
    }
    __syncthreads();
    buf ^= 1;
  }

  __syncthreads();
  u16* Ot = smem + w * 4096;
  float inv = 1.f / lsum;
  #pragma unroll
  for (int dt = 0; dt < 4; ++dt)
    #pragma unroll
    for (int r = 0; r < 16; ++r){
      int d = dt*32 + (r & 3) + 8*(r >> 2) + 4*hi;
      Ot[lane31*128 + (d ^ ((lane31 & 15) << 2))] = f2bf(acc[dt][r] * inv);
    }
  u16* outp = ctx + ((size_t)(b * S_ + q0w)) * HID_ + h * D_;
  #pragma unroll
  for (int it = 0; it < 16; ++it){
    int id = it * 64 + l;
    int q = id >> 5;
    int c4 = (id & 31) * 4;
    ushort4 vv = *(const ushort4*)(Ot + q*128 + (c4 ^ ((q & 15) << 2)));
    *(ushort4*)(outp + (size_t)q * HID_ + c4) = vv;
  }
}

extern "C" void kernel_launch(void* const* d_in, const int* in_sizes, int n_in,
                              void* d_out, int out_size, void* d_ws, size_t ws_size,
                              hipStream_t stream) {
  const float* x  = (const float*)d_in[0];
  const int*   pos = (const int*)d_in[2];
  const float* Wq = (const float*)d_in[3];
  const float* Wk = (const float*)d_in[4];
  const float* Wv = (const float*)d_in[5];
  const float* Wo = (const float*)d_in[6];

  char* ws = (char*)d_ws;
  u16* xb   = (u16*)(ws);                               // 32MB; reused as ctx after QKV
  u16* WT   = (u16*)(ws + ((size_t)32 << 20));          // 48MB: Wq^T|Wk^T|Wv^T (dead after QKV gemm)
  u16* WoT  = (u16*)(ws + ((size_t)80 << 20));          // 32MB
  u16* QKVb = (u16*)(ws + ((size_t)112 << 20));         // 48MB: [4096][6144]
  u16* Vtg  = (u16*)(ws + ((size_t)32 << 20));          // 8MB overlay on WT: [b*1024+vd][S]

  cast_f32_bf16<<<16384, 256, 0, stream>>>(x, xb, HID_ * M_);
  tcast_all<<<10240, 256, 0, stream>>>(Wq, Wk, Wv, Wo, WT, WoT);
  gemm192<<<512, 512, 0, stream>>>(xb, WT, QKVb, 6144, 16);
  rope_k<<<8192, 256, 0, stream>>>(QKVb + 4096, pos, 3, QSTR);   // K heads only; Q-RoPE fused in attn
  vtrans<<<dim3(32, 32), 256, 0, stream>>>(QKVb, Vtg);
  attn_k<<<dim3(64, 8), 512, 0, stream>>>(QKVb, Vtg, pos, xb);
  gemm256<true><<<256, 512, 0, stream>>>(xb, WoT, d_out, 4096, 16);
}

// Round 13
// 513.910 us; speedup vs baseline: 1.0546x; 1.0033x over previous
//
#include <hip/hip_runtime.h>
#include <cstdint>
#include <cstddef>

#define B_   2
#define S_   2048
#define HID_ 4096
#define H_   32
#define KV_  8
#define D_   128
#define M_   (B_*S_)      // 4096 tokens
#define QSTR 6144         // QKV combined row stride (H*D + 2*KV*D)

typedef __attribute__((ext_vector_type(8))) short bf16x8;
typedef __attribute__((ext_vector_type(4))) float f32x4;
typedef __attribute__((ext_vector_type(16))) float f32x16;
typedef __attribute__((ext_vector_type(4))) unsigned int u32x4;
typedef unsigned short u16;
typedef unsigned int   u32;

// softmax scale folded into exp2: SCALE * log2(e)
#define KSC (0.08838834764831845f * 1.4426950408889634f)

__device__ __forceinline__ float bf2f(u16 v){ u32 u = ((u32)v) << 16; return __builtin_bit_cast(float, u); }
__device__ __forceinline__ u16 f2bf(float f){
  u32 u = __builtin_bit_cast(u32, f);
  u32 r = u + 0x7fffu + ((u >> 16) & 1u);   // RNE
  return (u16)(r >> 16);
}

__device__ __forceinline__ void gload_lds16(const void* g, void* lds){
  __builtin_amdgcn_global_load_lds(
      (const __attribute__((address_space(1))) void*)g,
      (__attribute__((address_space(3))) void*)lds, 16, 0, 0);
}

#define BAR() __builtin_amdgcn_s_barrier()

// ---------------- cast fp32 -> bf16 (vectorized, grid-stride) ----------------
__global__ void cast_f32_bf16(const float* __restrict__ in, u16* __restrict__ out, int n){
  int stride = gridDim.x * blockDim.x * 4;
  for (int i = (blockIdx.x * blockDim.x + threadIdx.x) * 4; i < n; i += stride){
    float4 v = *(const float4*)(in + i);
    ushort4 o;
    o.x = f2bf(v.x); o.y = f2bf(v.y); o.z = f2bf(v.z); o.w = f2bf(v.w);
    *(ushort4*)(out + i) = o;
  }
}

// ---------------- merged transpose-cast of all 4 weights (one launch) ----------------
__global__ __launch_bounds__(256) void tcast_all(const float* __restrict__ Wq, const float* __restrict__ Wk,
                                                 const float* __restrict__ Wv, const float* __restrict__ Wo,
                                                 u16* __restrict__ WT, u16* __restrict__ WoT){
  int bid = blockIdx.x;
  const float* W; u16* Dp; int Nd, kx, ny;
  if (bid < 4096){       W = Wq; Dp = WT;                         Nd = 4096; kx = bid & 63;        ny = bid >> 6; }
  else if (bid < 5120){  W = Wk; Dp = WT + (size_t)4096 * 4096;   Nd = 1024; kx = (bid-4096) & 63; ny = (bid-4096) >> 6; }
  else if (bid < 6144){  W = Wv; Dp = WT + (size_t)5120 * 4096;   Nd = 1024; kx = (bid-5120) & 63; ny = (bid-5120) >> 6; }
  else {                 W = Wo; Dp = WoT;                        Nd = 4096; kx = (bid-6144) & 63; ny = (bid-6144) >> 6; }
  __shared__ __align__(16) u16 t[64][65];     // t[n][k]
  int k0 = kx * 64, n0 = ny * 64;
  int lx = threadIdx.x & 15, ly = threadIdx.x >> 4;
  #pragma unroll
  for (int rr = 0; rr < 4; ++rr){
    int r = rr * 16 + ly;                     // k-row in tile
    float4 v = *(const float4*)(W + (size_t)(k0 + r) * Nd + n0 + lx * 4);
    t[lx*4+0][r] = f2bf(v.x);
    t[lx*4+1][r] = f2bf(v.y);
    t[lx*4+2][r] = f2bf(v.z);
    t[lx*4+3][r] = f2bf(v.w);
  }
  __syncthreads();
  #pragma unroll
  for (int rr = 0; rr < 4; ++rr){
    int r = rr * 16 + ly;                     // n-row in tile
    ushort4 o;
    o.x = t[r][lx*4+0]; o.y = t[r][lx*4+1]; o.z = t[r][lx*4+2]; o.w = t[r][lx*4+3];
    *(ushort4*)(Dp + (size_t)(n0 + r) * 4096 + k0 + lx * 4) = o;
  }
}

// ------- merged: V-transpose (blocks 0..1023) + K-RoPE (blocks 1024..9215) -------
__global__ __launch_bounds__(256) void rope_vtrans(u16* __restrict__ QKV, u16* __restrict__ Vt,
                                                   const int* __restrict__ pos){
  int bid = blockIdx.x;
  if (bid < 1024){
    // vtrans: QKV[t][5120 + vd] -> Vt[b*1024+vd][s]
    __shared__ __align__(16) u16 t[64][65];
    int stile = bid & 31;
    int rest = bid >> 5;
    int b = rest >> 4, vt = rest & 15;
    int s0 = stile * 64, c0 = vt * 64;
    int lx = threadIdx.x & 15, ly = threadIdx.x >> 4;
    #pragma unroll
    for (int rr = 0; rr < 4; ++rr){
      int r = rr * 16 + ly;                 // s-row
      ushort4 v = *(const ushort4*)(QKV + (size_t)(b*S_ + s0 + r) * QSTR + 5120 + c0 + lx*4);
      t[lx*4+0][r]=v.x; t[lx*4+1][r]=v.y; t[lx*4+2][r]=v.z; t[lx*4+3][r]=v.w;
    }
    __syncthreads();
    #pragma unroll
    for (int rr = 0; rr < 4; ++rr){
      int r = rr * 16 + ly;                 // vd-row
      ushort4 o;
      o.x=t[r][lx*4+0]; o.y=t[r][lx*4+1]; o.z=t[r][lx*4+2]; o.w=t[r][lx*4+3];
      *(ushort4*)(Vt + (size_t)(b*1024 + c0 + r) * S_ + s0 + lx*4) = o;
    }
  } else {
    // K-RoPE in-place, 8 KV heads
    int idx = (bid - 1024) * 256 + threadIdx.x;
    int i = idx & 63;
    int h = (idx >> 6) & 7;
    int t = idx >> 9;
    u16* p0 = QKV + 4096 + (size_t)t * QSTR + h * D_ + i;
    float x1 = bf2f(p0[0]), x2 = bf2f(p0[64]);
    float fpos = (float)pos[t];
    float invf = exp2f(-(float)(2 * i) * (13.287712379549449f / 128.0f));
    float f = fpos * invf;
    float sv = __sinf(f), cv = __cosf(f);
    p0[0]  = f2bf(x1 * cv - x2 * sv);
    p0[64] = f2bf(x2 * cv + x1 * sv);
  }
}

// ============ gemm256 (R8 proven): BM=BN=256, BK=64, rolled loop, no spill ============
#define STG_A(PB, HALF, KT) do{ \
  gload_lds16(Ag + off0 + (size_t)(HALF)*1048576 + (size_t)(KT)*128, \
              (char*)smem + (PB)*32768 + (HALF)*16384 + w*1024); \
  gload_lds16(Ag + off0 + 524288 + (size_t)(HALF)*1048576 + (size_t)(KT)*128, \
              (char*)smem + (PB)*32768 + (HALF)*16384 + 8192 + w*1024); }while(0)
#define STG_B(PB, HALF, KT) do{ \
  gload_lds16(Bg + off0 + (size_t)(HALF)*1048576 + (size_t)(KT)*128, \
              (char*)smem + 65536 + (PB)*32768 + (HALF)*16384 + w*1024); \
  gload_lds16(Bg + off0 + 524288 + (size_t)(HALF)*1048576 + (size_t)(KT)*128, \
              (char*)smem + 65536 + (PB)*32768 + (HALF)*16384 + 8192 + w*1024); }while(0)

#define RD_A(DST, PP, HALF) do{ \
  _Pragma("unroll") for (int ks = 0; ks < 2; ++ks) \
  _Pragma("unroll") for (int m = 0; m < 4; ++m) \
    DST[ks][m] = *(const bf16x8*)&smem[(PP)*16384 + (HALF)*8192 + aRowBase + m*1024 + csw[ks]]; }while(0)
#define RD_B(DST, PP, HALF) do{ \
  _Pragma("unroll") for (int ks = 0; ks < 2; ++ks) \
  _Pragma("unroll") for (int n = 0; n < 2; ++n) \
    DST[ks][n] = *(const bf16x8*)&smem[32768 + (PP)*16384 + (HALF)*8192 + bRowBase + n*1024 + csw[ks]]; }while(0)

template<int MO, int NO>
__device__ __forceinline__ void mfma_quad(f32x4 (&acc)[8][4],
                                          const bf16x8 (&af)[2][4], const bf16x8 (&bf)[2][2]){
  __builtin_amdgcn_s_setprio(1);
  #pragma unroll
  for (int ks = 0; ks < 2; ++ks)
    #pragma unroll
    for (int m = 0; m < 4; ++m)
      #pragma unroll
      for (int n = 0; n < 2; ++n)
        acc[MO+m][NO+n] = __builtin_amdgcn_mfma_f32_16x16x32_bf16(af[ks][m], bf[ks][n], acc[MO+m][NO+n], 0, 0, 0);
  __builtin_amdgcn_s_setprio(0);
}

template<bool OUTF32>
__global__ __launch_bounds__(512, 2) void gemm256(const u16* __restrict__ A, const u16* __restrict__ Bt,
                                                  void* __restrict__ C, int Nn, int mt){
  __shared__ __align__(16) u16 smem[65536];   // 128 KB
  const int tid = threadIdx.x;
  const int l = tid & 63, w = tid >> 6;
  const int lr = l & 15, lk = l >> 4;
  const int wr = w >> 2, wc = w & 3;

  const int nwg = gridDim.x;
  const int sbid = ((int)blockIdx.x & 7) * (nwg >> 3) + ((int)blockIdx.x >> 3);
  const int bx = sbid % mt, by = sbid / mt;
  const size_t arow0 = (size_t)bx * 256;
  const size_t brow0 = (size_t)by * 256;
  const char* Ag = (const char*)(A + arow0 * 4096);
  const char* Bg = (const char*)(Bt + brow0 * 4096);

  const size_t off0 = (size_t)(w * 8 + (l >> 3)) * 8192 + (size_t)(((l & 7) ^ (l >> 3)) << 4);

  const int aRowBase = (wr*64 + lr) * 64;
  const int bRowBase = (wc*32 + lr) * 64;
  int csw[2];
  csw[0] = ((lk     ) ^ (lr & 7)) << 3;
  csw[1] = ((lk + 4) ^ (lr & 7)) << 3;

  f32x4 acc[8][4];
  #pragma unroll
  for (int i = 0; i < 8; ++i)
    #pragma unroll
    for (int j = 0; j < 4; ++j){ acc[i][j][0]=0.f; acc[i][j][1]=0.f; acc[i][j][2]=0.f; acc[i][j][3]=0.f; }

  STG_A(0, 0, 0); STG_B(0, 0, 0); STG_A(0, 1, 0); STG_B(0, 1, 0);
  STG_A(1, 0, 1); STG_B(1, 0, 1); STG_A(1, 1, 1); STG_B(1, 1, 1);
  asm volatile("s_waitcnt vmcnt(8)" ::: "memory");
  BAR();
  bf16x8 a0c[2][4], b0c[2][2], a1f[2][4], b1f[2][2];
  RD_A(a0c, 0, 0); RD_B(b0c, 0, 0);

  for (int t = 0; t < 64; ++t){
    const int P = t & 1;
    RD_A(a1f, P, 1);
    BAR();
    mfma_quad<0,0>(acc, a0c, b0c);
    BAR();
    if (t < 62){ STG_A(P, 0, t+2); STG_B(P, 0, t+2); }
    RD_B(b1f, P, 1);
    BAR();
    mfma_quad<4,0>(acc, a1f, b0c);
    BAR();
    if (t < 62){
      STG_A(P, 1, t+2);
      asm volatile("s_waitcnt vmcnt(6)" ::: "memory");
    } else if (t == 62){
      asm volatile("s_waitcnt vmcnt(0)" ::: "memory");
    }
    BAR();
    mfma_quad<4,2>(acc, a1f, b1f);
    BAR();
    if (t < 62){ STG_B(P, 1, t+2); }
    BAR();
    mfma_quad<0,2>(acc, a0c, b1f);
    if (t < 63){ RD_A(a0c, P^1, 0); RD_B(b0c, P^1, 0); }
    BAR();
  }

  #pragma unroll
  for (int mh = 0; mh < 2; ++mh)
    #pragma unroll
    for (int m = 0; m < 4; ++m)
      #pragma unroll
      for (int nh = 0; nh < 2; ++nh)
        #pragma unroll
        for (int n = 0; n < 2; ++n)
          #pragma unroll
          for (int j = 0; j < 4; ++j){
            size_t gr = arow0 + mh*128 + wr*64 + m*16 + lk*4 + j;
            size_t gc = brow0 + nh*128 + wc*32 + n*16 + lr;
            float v = acc[mh*4+m][nh*2+n][j];
            if (OUTF32) ((float*)C)[gr * Nn + gc] = v;
            else        ((u16*)C)[gr * Nn + gc] = f2bf(v);
          }
}

// ============ gemm192 (R8 proven, 45% MfmaUtil): BM=256, BN=192, BK=64, rolled ============
#define STG_B3(PB, KT) do{ \
  _Pragma("unroll") for (int r2 = 0; r2 < 3; ++r2) \
    gload_lds16(Bg + bsrc3[r2] + (size_t)(KT)*128, \
                (char*)smem + 65536 + (PB)*24576 + r2*8192 + w*1024); }while(0)

#define RD_B0(DST, PP) do{ \
  _Pragma("unroll") for (int ks = 0; ks < 2; ++ks) \
  _Pragma("unroll") for (int n = 0; n < 2; ++n) \
    DST[ks][n] = *(const bf16x8*)&smem[32768 + (PP)*12288 + bRowBase + n*1024 + csw[ks]]; }while(0)
#define RD_B1(DST, PP) do{ \
  _Pragma("unroll") for (int ks = 0; ks < 2; ++ks) \
    DST[ks] = *(const bf16x8*)&smem[32768 + (PP)*12288 + bRowBase + 2048 + csw[ks]]; }while(0)

__device__ __forceinline__ void mfma_pair16(f32x4 (&acc)[8][3], int MO,
                                            const bf16x8 (&af)[2][4], const bf16x8 (&bf)[2][2]){
  __builtin_amdgcn_s_setprio(1);
  #pragma unroll
  for (int ks = 0; ks < 2; ++ks)
    #pragma unroll
    for (int m = 0; m < 4; ++m)
      #pragma unroll
      for (int n = 0; n < 2; ++n)
        acc[MO+m][n] = __builtin_amdgcn_mfma_f32_16x16x32_bf16(af[ks][m], bf[ks][n], acc[MO+m][n], 0, 0, 0);
  __builtin_amdgcn_s_setprio(0);
}
__device__ __forceinline__ void mfma_pair8(f32x4 (&acc)[8][3], int MO,
                                           const bf16x8 (&af)[2][4], const bf16x8 (&bf)[2]){
  __builtin_amdgcn_s_setprio(1);
  #pragma unroll
  for (int ks = 0; ks < 2; ++ks)
    #pragma unroll
    for (int m = 0; m < 4; ++m)
      acc[MO+m][2] = __builtin_amdgcn_mfma_f32_16x16x32_bf16(af[ks][m], bf[ks], acc[MO+m][2], 0, 0, 0);
  __builtin_amdgcn_s_setprio(0);
}

__global__ __launch_bounds__(512, 2) void gemm192(const u16* __restrict__ A, const u16* __restrict__ Bt,
                                                  u16* __restrict__ C, int Nn, int mt){
  __shared__ __align__(16) u16 smem[57344];   // 112 KB
  const int tid = threadIdx.x;
  const int l = tid & 63, w = tid >> 6;
  const int lr = l & 15, lk = l >> 4;
  const int wr = w >> 2, wc = w & 3;

  const int nwg = gridDim.x;
  const int sbid = ((int)blockIdx.x & 7) * (nwg >> 3) + ((int)blockIdx.x >> 3);
  const int bx = sbid % mt, by = sbid / mt;
  const size_t arow0 = (size_t)bx * 256;
  const size_t bcol0 = (size_t)by * 192;
  const char* Ag = (const char*)(A + arow0 * 4096);
  const char* Bg = (const char*)(Bt + bcol0 * 4096);

  const size_t off0 = (size_t)(w * 8 + (l >> 3)) * 8192 + (size_t)(((l & 7) ^ (l >> 3)) << 4);
  size_t bsrc3[3];
  #pragma unroll
  for (int r2 = 0; r2 < 3; ++r2){
    int idx = r2 * 512 + tid;
    int row = idx >> 3, ch = idx & 7;
    bsrc3[r2] = (size_t)row * 8192 + (size_t)((ch ^ (row & 7)) << 4);
  }

  const int aRowBase = (wr*64 + lr) * 64;
  const int bRowBase = (wc*48 + lr) * 64;
  int csw[2];
  csw[0] = ((lk     ) ^ (lr & 7)) << 3;
  csw[1] = ((lk + 4) ^ (lr & 7)) << 3;

  f32x4 acc[8][3];
  #pragma unroll
  for (int i = 0; i < 8; ++i)
    #pragma unroll
    for (int j = 0; j < 3; ++j){ acc[i][j][0]=0.f; acc[i][j][1]=0.f; acc[i][j][2]=0.f; acc[i][j][3]=0.f; }

  STG_A(0, 0, 0); STG_A(0, 1, 0); STG_B3(0, 0);
  STG_A(1, 0, 1); STG_A(1, 1, 1); STG_B3(1, 1);
  asm volatile("s_waitcnt vmcnt(7)" ::: "memory");
  BAR();
  bf16x8 a0c[2][4], a1f[2][4], b0c[2][2], b1f[2];
  RD_A(a0c, 0, 0); RD_B0(b0c, 0);

  for (int t = 0; t < 64; ++t){
    const int P = t & 1;
    RD_A(a1f, P, 1);
    BAR();
    mfma_pair16(acc, 0, a0c, b0c);
    BAR();
    if (t < 62){ STG_A(P, 0, t+2); }
    RD_B1(b1f, P);
    BAR();
    mfma_pair16(acc, 4, a1f, b0c);
    BAR();
    if (t < 62){
      STG_A(P, 1, t+2);
      asm volatile("s_waitcnt vmcnt(4)" ::: "memory");
    } else if (t == 62){
      asm volatile("s_waitcnt vmcnt(0)" ::: "memory");
    }
    BAR();
    mfma_pair8(acc, 4, a1f, b1f);
    BAR();
    if (t < 62){ STG_B3(P, t+2); }
    BAR();
    mfma_pair8(acc, 0, a0c, b1f);
    if (t < 63){ RD_A(a0c, P^1, 0); RD_B0(b0c, P^1); }
    BAR();
  }

  #pragma unroll
  for (int mh = 0; mh < 2; ++mh)
    #pragma unroll
    for (int m = 0; m < 4; ++m)
      #pragma unroll
      for (int f = 0; f < 3; ++f)
        #pragma unroll
        for (int j = 0; j < 4; ++j){
          size_t gr = arow0 + mh*128 + wr*64 + m*16 + lk*4 + j;
          size_t gc = bcol0 + wc*48 + f*16 + lr;
          C[gr * Nn + gc] = f2bf(acc[mh*4+m][f][j]);
        }
}

// ---------------- flash attention: 8 waves x 32 q-rows, KVBLK=64, 32x32x16 MFMA ----------------
// fused Q-RoPE, defer-max (T13), CU-pair-balanced qb order, setprio (T5),
// wave-uniform skip of fully-masked s1 half-tile on the diagonal.
__global__ __launch_bounds__(512, 2) void attn_k(const u16* __restrict__ QKV,
                                                 const u16* __restrict__ Vtg,
                                                 const int* __restrict__ pos,
                                                 u16* __restrict__ ctx){
  __shared__ __align__(16) u16 smem[32768];   // 64 KB
  const int tid = threadIdx.x;
  const int l = tid & 63, w = tid >> 6;
  const int lane31 = l & 31, hi = l >> 5;
  const int hb = blockIdx.x;
  const int b = hb >> 5, h = hb & 31, kvh = h >> 2;
  const int y = blockIdx.y;
  const int qb = (y < 4) ? (7 - y) : (y - 4);   // pairs (7,0),(6,1),(5,2),(4,3) co-resident
  const int q0w = qb * 256 + w * 32;
  const int qg = q0w + lane31;

  const u16* Qp = QKV + (size_t)b * S_ * QSTR + (size_t)h * D_;
  const char* Kp = (const char*)(QKV + (size_t)b * S_ * QSTR + 4096 + (size_t)kvh * D_);
  const char* Vp = (const char*)(Vtg + ((size_t)b * 1024 + kvh * 128) * S_);

  bf16x8 qf[8];
  #pragma unroll
  for (int dt = 0; dt < 8; ++dt)
    qf[dt] = *(const bf16x8*)(Qp + (size_t)qg * QSTR + dt * 16 + hi * 8);

  // fused Q-RoPE: qf[dt][j] holds d = dt*16 + hi*8 + j; pairs (d, d+64) = (qf[dt], qf[dt+4])
  {
    float fp = (float)pos[b * S_ + qg];
    #pragma unroll
    for (int dt = 0; dt < 4; ++dt){
      bf16x8 lo = qf[dt], hi8 = qf[dt + 4], nlo, nhi;
      #pragma unroll
      for (int j = 0; j < 8; ++j){
        int d = dt * 16 + hi * 8 + j;
        float invf = exp2f(-(float)(2 * d) * (13.287712379549449f / 128.0f));
        float f = fp * invf;
        float sv = __sinf(f), cv = __cosf(f);
        float x1 = bf2f((u16)lo[j]), x2 = bf2f((u16)hi8[j]);
        nlo[j] = (short)f2bf(x1 * cv - x2 * sv);
        nhi[j] = (short)f2bf(x2 * cv + x1 * sv);
      }
      qf[dt] = nlo; qf[dt + 4] = nhi;
    }
  }

  const int krow0 = (2*w)*4 + (l >> 4), krow1 = krow0 + 4;
  const size_t koff0 = (size_t)krow0 * (QSTR*2) + (((l & 15) << 4) ^ ((krow0 & 7) << 4));
  const size_t koff1 = (size_t)krow1 * (QSTR*2) + (((l & 15) << 4) ^ ((krow1 & 7) << 4));
  const int vrow0 = (2*w)*8 + (l >> 3), vrow1 = vrow0 + 8;
  const size_t voff0 = (size_t)vrow0 * (S_*2) + (((l & 7) << 4) ^ ((vrow0 & 7) << 4));
  const size_t voff1 = (size_t)vrow1 * (S_*2) + (((l & 7) << 4) ^ ((vrow1 & 7) << 4));

  f32x16 acc[4];
  #pragma unroll
  for (int dt = 0; dt < 4; ++dt)
    #pragma unroll
    for (int i = 0; i < 16; ++i) acc[dt][i] = 0.f;
  float mrow = -3e38f, lsum = 0.f;

  const int nt = qb * 4 + 4;

  auto STAGE = [&](int t, int bufn){
    char* Kb = (char*)smem + bufn * 16384;
    char* Vb = (char*)smem + 32768 + bufn * 16384;
    size_t kb = (size_t)t * 64 * (QSTR*2);
    size_t vb = (size_t)t * 128;
    gload_lds16(Kp + kb + koff0, Kb + (2*w)*1024);
    gload_lds16(Kp + kb + koff1, Kb + (2*w+1)*1024);
    gload_lds16(Vp + vb + voff0, Vb + (2*w)*1024);
    gload_lds16(Vp + vb + voff1, Vb + (2*w+1)*1024);
  };

  STAGE(0, 0);
  __syncthreads();
  int buf = 0;
  for (int t = 0; t < nt; ++t){
    if (t + 1 < nt) STAGE(t + 1, buf ^ 1);
    const int kbase = t * 64;
    if (kbase <= q0w + 31){
      const char* Kb = (const char*)smem + buf * 16384;
      const char* Vb = (const char*)smem + 32768 + buf * 16384;
      const int swz = (lane31 & 7) << 4;

      f32x16 s0, s1;
      #pragma unroll
      for (int i = 0; i < 16; ++i){ s0[i] = 0.f; s1[i] = 0.f; }
      const bool doS1 = (kbase + 32 <= q0w + 31);   // wave-uniform: s1 half has any live column
      __builtin_amdgcn_s_setprio(1);
      #pragma unroll
      for (int dt = 0; dt < 8; ++dt){
        bf16x8 kf = *(const bf16x8*)(Kb + lane31*256 + ((dt*32 + hi*16) ^ swz));
        s0 = __builtin_amdgcn_mfma_f32_32x32x16_bf16(kf, qf[dt], s0, 0, 0, 0);
      }
      if (doS1){
        #pragma unroll
        for (int dt = 0; dt < 8; ++dt){
          bf16x8 kf = *(const bf16x8*)(Kb + (32 + lane31)*256 + ((dt*32 + hi*16) ^ swz));
          s1 = __builtin_amdgcn_mfma_f32_32x32x16_bf16(kf, qf[dt], s1, 0, 0, 0);
        }
      }
      __builtin_amdgcn_s_setprio(0);

      if (kbase + 63 > q0w){
        int thr = qg - kbase;
        #pragma unroll
        for (int r = 0; r < 16; ++r){
          int kc = (r & 3) + 8*(r >> 2) + 4*hi;
          s0[r] = (kc > thr)      ? -1e30f : s0[r];
          s1[r] = (kc + 32 > thr) ? -1e30f : s1[r];
        }
      }

      float tmax = s0[0];
      #pragma unroll
      for (int r = 1; r < 16; ++r) tmax = fmaxf(tmax, s0[r]);
      #pragma unroll
      for (int r = 0; r < 16; ++r) tmax = fmaxf(tmax, s1[r]);
      tmax = fmaxf(tmax, __shfl_xor(tmax, 32));
      // defer-max (T13): skip O-rescale while growth <= 8 exp2-bits (62.7 raw)
      if (!__all(tmax - mrow <= 62.7f)){
        float mn = fmaxf(mrow, tmax);
        float rf = exp2f((mrow - mn) * KSC);
        mrow = mn;
        lsum *= rf;
        #pragma unroll
        for (int dt = 0; dt < 4; ++dt)
          #pragma unroll
          for (int i = 0; i < 16; ++i) acc[dt][i] *= rf;
      }
      float ps = 0.f;
      #pragma unroll
      for (int r = 0; r < 16; ++r){
        float a = exp2f((s0[r] - mrow) * KSC);
        float c = exp2f((s1[r] - mrow) * KSC);
        s0[r] = a; s1[r] = c; ps += a + c;
      }
      ps += __shfl_xor(ps, 32);
      lsum += ps;

      u32 pw[16];
      #pragma unroll
      for (int g = 0; g < 4; ++g){
        pw[2*g]     = (u32)f2bf(s0[4*g])   | ((u32)f2bf(s0[4*g+1]) << 16);
        pw[2*g+1]   = (u32)f2bf(s0[4*g+2]) | ((u32)f2bf(s0[4*g+3]) << 16);
        pw[8+2*g]   = (u32)f2bf(s1[4*g])   | ((u32)f2bf(s1[4*g+1]) << 16);
        pw[8+2*g+1] = (u32)f2bf(s1[4*g+2]) | ((u32)f2bf(s1[4*g+3]) << 16);
      }

      #pragma unroll
      for (int kt = 0; kt < 4; ++kt){
        u32 W0 = pw[kt*4+0], W1 = pw[kt*4+1], W2 = pw[kt*4+2], W3 = pw[kt*4+3];
        u32 x0 = hi ? W0 : W2;
        u32 x1 = hi ? W1 : W3;
        u32 y0 = __shfl_xor(x0, 32);
        u32 y1 = __shfl_xor(x1, 32);
        u32 w0 = hi ? y0 : W0;
        u32 w1 = hi ? y1 : W1;
        u32 w2 = hi ? W2 : y0;
        u32 w3 = hi ? W3 : y1;
        u32x4 pk; pk[0]=w0; pk[1]=w1; pk[2]=w2; pk[3]=w3;
        bf16x8 pa = __builtin_bit_cast(bf16x8, pk);
        __builtin_amdgcn_s_setprio(1);
        #pragma unroll
        for (int dt = 0; dt < 4; ++dt){
          bf16x8 vf = *(const bf16x8*)(Vb + (dt*32 + lane31)*128 + ((kt*32 + hi*16) ^ swz));
          acc[dt] = __builtin_amdgcn_mfma_f32_32x32x16_bf16(vf, pa, acc[dt], 0, 0, 0);
        }
        __builtin_amdgcn_s_setprio(0);
      }
    }
    __syncthreads();
    buf ^= 1;
  }

  __syncthreads();
  u16* Ot = smem + w * 4096;
  float inv = 1.f / lsum;
  #pragma unroll
  for (int dt = 0; dt < 4; ++dt)
    #pragma unroll
    for (int r = 0; r < 16; ++r){
      int d = dt*32 + (r & 3) + 8*(r >> 2) + 4*hi;
      Ot[lane31*128 + (d ^ ((lane31 & 15) << 2))] = f2bf(acc[dt][r] * inv);
    }
  u16* outp = ctx + ((size_t)(b * S_ + q0w)) * HID_ + h * D_;
  #pragma unroll
  for (int it = 0; it < 16; ++it){
    int id = it * 64 + l;
    int q = id >> 5;
    int c4 = (id & 31) * 4;
    ushort4 vv = *(const ushort4*)(Ot + q*128 + (c4 ^ ((q & 15) << 2)));
    *(ushort4*)(outp + (size_t)q * HID_ + c4) = vv;
  }
}

extern "C" void kernel_launch(void* const* d_in, const int* in_sizes, int n_in,
                              void* d_out, int out_size, void* d_ws, size_t ws_size,
                              hipStream_t stream) {
  const float* x  = (const float*)d_in[0];
  const int*   pos = (const int*)d_in[2];
  const float* Wq = (const float*)d_in[3];
  const float* Wk = (const float*)d_in[4];
  const float* Wv = (const float*)d_in[5];
  const float* Wo = (const float*)d_in[6];

  char* ws = (char*)d_ws;
  u16* xb   = (u16*)(ws);                               // 32MB; reused as ctx after QKV
  u16* WT   = (u16*)(ws + ((size_t)32 << 20));          // 48MB: Wq^T|Wk^T|Wv^T (dead after QKV gemm)
  u16* WoT  = (u16*)(ws + ((size_t)80 << 20));          // 32MB
  u16* QKVb = (u16*)(ws + ((size_t)112 << 20));         // 48MB: [4096][6144]
  u16* Vtg  = (u16*)(ws + ((size_t)32 << 20));          // 8MB overlay on WT: [b*1024+vd][S]

  cast_f32_bf16<<<2048, 256, 0, stream>>>(x, xb, HID_ * M_);
  tcast_all<<<10240, 256, 0, stream>>>(Wq, Wk, Wv, Wo, WT, WoT);
  gemm192<<<512, 512, 0, stream>>>(xb, WT, QKVb, 6144, 16);
  rope_vtrans<<<9216, 256, 0, stream>>>(QKVb, Vtg, pos);
  attn_k<<<dim3(64, 8), 512, 0, stream>>>(QKVb, Vtg, pos, xb);
  gemm256<true><<<256, 512, 0, stream>>>(xb, WoT, d_out, 4096, 16);
}

// Round 14
// 509.873 us; speedup vs baseline: 1.0629x; 1.0079x over previous
//
#include <hip/hip_runtime.h>
#include <cstdint>
#include <cstddef>

#define B_   2
#define S_   2048
#define HID_ 4096
#define H_   32
#define KV_  8
#define D_   128
#define M_   (B_*S_)      // 4096 tokens
#define QSTR 6144         // QKV combined row stride (H*D + 2*KV*D)

typedef __attribute__((ext_vector_type(8))) short bf16x8;
typedef __attribute__((ext_vector_type(4))) float f32x4;
typedef __attribute__((ext_vector_type(16))) float f32x16;
typedef __attribute__((ext_vector_type(4))) unsigned int u32x4;
typedef unsigned short u16;
typedef unsigned int   u32;

// softmax scale folded into exp2: SCALE * log2(e)
#define KSC (0.08838834764831845f * 1.4426950408889634f)

__device__ __forceinline__ float bf2f(u16 v){ u32 u = ((u32)v) << 16; return __builtin_bit_cast(float, u); }
__device__ __forceinline__ u16 f2bf(float f){
  u32 u = __builtin_bit_cast(u32, f);
  u32 r = u + 0x7fffu + ((u >> 16) & 1u);   // RNE
  return (u16)(r >> 16);
}

__device__ __forceinline__ void gload_lds16(const void* g, void* lds){
  __builtin_amdgcn_global_load_lds(
      (const __attribute__((address_space(1))) void*)g,
      (__attribute__((address_space(3))) void*)lds, 16, 0, 0);
}

#define BAR() __builtin_amdgcn_s_barrier()

// ---- merged prep: x-cast (blocks 0..2047) + all-weight transpose-cast (blocks 2048..12287) ----
// Both memory-bound & independent -> run concurrently at combined HBM roofline.
__global__ __launch_bounds__(256) void prep(const float* __restrict__ x, u16* __restrict__ xb,
                                            const float* __restrict__ Wq, const float* __restrict__ Wk,
                                            const float* __restrict__ Wv, const float* __restrict__ Wo,
                                            u16* __restrict__ WT, u16* __restrict__ WoT){
  int bid = blockIdx.x;
  if (bid < 2048){
    // cast: 2048 blocks x 8192 elements = 16,777,216 = HID_*M_ exactly
    int base = bid * 8192 + threadIdx.x * 4;
    #pragma unroll
    for (int k = 0; k < 8; ++k){
      int i = base + k * 1024;
      float4 v = *(const float4*)(x + i);
      ushort4 o;
      o.x = f2bf(v.x); o.y = f2bf(v.y); o.z = f2bf(v.z); o.w = f2bf(v.w);
      *(ushort4*)(xb + i) = o;
    }
    return;
  }
  int tb = bid - 2048;
  const float* W; u16* Dp; int Nd, kx, ny;
  if (tb < 4096){       W = Wq; Dp = WT;                         Nd = 4096; kx = tb & 63;        ny = tb >> 6; }
  else if (tb < 5120){  W = Wk; Dp = WT + (size_t)4096 * 4096;   Nd = 1024; kx = (tb-4096) & 63; ny = (tb-4096) >> 6; }
  else if (tb < 6144){  W = Wv; Dp = WT + (size_t)5120 * 4096;   Nd = 1024; kx = (tb-5120) & 63; ny = (tb-5120) >> 6; }
  else {                W = Wo; Dp = WoT;                        Nd = 4096; kx = (tb-6144) & 63; ny = (tb-6144) >> 6; }
  __shared__ __align__(16) u16 t[64][65];     // t[n][k]
  int k0 = kx * 64, n0 = ny * 64;
  int lx = threadIdx.x & 15, ly = threadIdx.x >> 4;
  #pragma unroll
  for (int rr = 0; rr < 4; ++rr){
    int r = rr * 16 + ly;                     // k-row in tile
    float4 v = *(const float4*)(W + (size_t)(k0 + r) * Nd + n0 + lx * 4);
    t[lx*4+0][r] = f2bf(v.x);
    t[lx*4+1][r] = f2bf(v.y);
    t[lx*4+2][r] = f2bf(v.z);
    t[lx*4+3][r] = f2bf(v.w);
  }
  __syncthreads();
  #pragma unroll
  for (int rr = 0; rr < 4; ++rr){
    int r = rr * 16 + ly;                     // n-row in tile
    ushort4 o;
    o.x = t[r][lx*4+0]; o.y = t[r][lx*4+1]; o.z = t[r][lx*4+2]; o.w = t[r][lx*4+3];
    *(ushort4*)(Dp + (size_t)(n0 + r) * 4096 + k0 + lx * 4) = o;
  }
}

// ------- merged: V-transpose (blocks 0..1023) + K-RoPE (blocks 1024..9215) -------
__global__ __launch_bounds__(256) void rope_vtrans(u16* __restrict__ QKV, u16* __restrict__ Vt,
                                                   const int* __restrict__ pos){
  int bid = blockIdx.x;
  if (bid < 1024){
    __shared__ __align__(16) u16 t[64][65];
    int stile = bid & 31;
    int rest = bid >> 5;
    int b = rest >> 4, vt = rest & 15;
    int s0 = stile * 64, c0 = vt * 64;
    int lx = threadIdx.x & 15, ly = threadIdx.x >> 4;
    #pragma unroll
    for (int rr = 0; rr < 4; ++rr){
      int r = rr * 16 + ly;                 // s-row
      ushort4 v = *(const ushort4*)(QKV + (size_t)(b*S_ + s0 + r) * QSTR + 5120 + c0 + lx*4);
      t[lx*4+0][r]=v.x; t[lx*4+1][r]=v.y; t[lx*4+2][r]=v.z; t[lx*4+3][r]=v.w;
    }
    __syncthreads();
    #pragma unroll
    for (int rr = 0; rr < 4; ++rr){
      int r = rr * 16 + ly;                 // vd-row
      ushort4 o;
      o.x=t[r][lx*4+0]; o.y=t[r][lx*4+1]; o.z=t[r][lx*4+2]; o.w=t[r][lx*4+3];
      *(ushort4*)(Vt + (size_t)(b*1024 + c0 + r) * S_ + s0 + lx*4) = o;
    }
  } else {
    int idx = (bid - 1024) * 256 + threadIdx.x;
    int i = idx & 63;
    int h = (idx >> 6) & 7;
    int t = idx >> 9;
    u16* p0 = QKV + 4096 + (size_t)t * QSTR + h * D_ + i;
    float x1 = bf2f(p0[0]), x2 = bf2f(p0[64]);
    float fpos = (float)pos[t];
    float invf = exp2f(-(float)(2 * i) * (13.287712379549449f / 128.0f));
    float f = fpos * invf;
    float sv = __sinf(f), cv = __cosf(f);
    p0[0]  = f2bf(x1 * cv - x2 * sv);
    p0[64] = f2bf(x2 * cv + x1 * sv);
  }
}

// ============ gemm256 (R8 proven): BM=BN=256, BK=64, rolled loop, no spill ============
#define STG_A(PB, HALF, KT) do{ \
  gload_lds16(Ag + off0 + (size_t)(HALF)*1048576 + (size_t)(KT)*128, \
              (char*)smem + (PB)*32768 + (HALF)*16384 + w*1024); \
  gload_lds16(Ag + off0 + 524288 + (size_t)(HALF)*1048576 + (size_t)(KT)*128, \
              (char*)smem + (PB)*32768 + (HALF)*16384 + 8192 + w*1024); }while(0)
#define STG_B(PB, HALF, KT) do{ \
  gload_lds16(Bg + off0 + (size_t)(HALF)*1048576 + (size_t)(KT)*128, \
              (char*)smem + 65536 + (PB)*32768 + (HALF)*16384 + w*1024); \
  gload_lds16(Bg + off0 + 524288 + (size_t)(HALF)*1048576 + (size_t)(KT)*128, \
              (char*)smem + 65536 + (PB)*32768 + (HALF)*16384 + 8192 + w*1024); }while(0)

#define RD_A(DST, PP, HALF) do{ \
  _Pragma("unroll") for (int ks = 0; ks < 2; ++ks) \
  _Pragma("unroll") for (int m = 0; m < 4; ++m) \
    DST[ks][m] = *(const bf16x8*)&smem[(PP)*16384 + (HALF)*8192 + aRowBase + m*1024 + csw[ks]]; }while(0)
#define RD_B(DST, PP, HALF) do{ \
  _Pragma("unroll") for (int ks = 0; ks < 2; ++ks) \
  _Pragma("unroll") for (int n = 0; n < 2; ++n) \
    DST[ks][n] = *(const bf16x8*)&smem[32768 + (PP)*16384 + (HALF)*8192 + bRowBase + n*1024 + csw[ks]]; }while(0)

template<int MO, int NO>
__device__ __forceinline__ void mfma_quad(f32x4 (&acc)[8][4],
                                          const bf16x8 (&af)[2][4], const bf16x8 (&bf)[2][2]){
  __builtin_amdgcn_s_setprio(1);
  #pragma unroll
  for (int ks = 0; ks < 2; ++ks)
    #pragma unroll
    for (int m = 0; m < 4; ++m)
      #pragma unroll
      for (int n = 0; n < 2; ++n)
        acc[MO+m][NO+n] = __builtin_amdgcn_mfma_f32_16x16x32_bf16(af[ks][m], bf[ks][n], acc[MO+m][NO+n], 0, 0, 0);
  __builtin_amdgcn_s_setprio(0);
}

template<bool OUTF32>
__global__ __launch_bounds__(512, 2) void gemm256(const u16* __restrict__ A, const u16* __restrict__ Bt,
                                                  void* __restrict__ C, int Nn, int mt){
  __shared__ __align__(16) u16 smem[65536];   // 128 KB
  const int tid = threadIdx.x;
  const int l = tid & 63, w = tid >> 6;
  const int lr = l & 15, lk = l >> 4;
  const int wr = w >> 2, wc = w & 3;

  const int nwg = gridDim.x;
  const int sbid = ((int)blockIdx.x & 7) * (nwg >> 3) + ((int)blockIdx.x >> 3);
  const int bx = sbid % mt, by = sbid / mt;
  const size_t arow0 = (size_t)bx * 256;
  const size_t brow0 = (size_t)by * 256;
  const char* Ag = (const char*)(A + arow0 * 4096);
  const char* Bg = (const char*)(Bt + brow0 * 4096);

  const size_t off0 = (size_t)(w * 8 + (l >> 3)) * 8192 + (size_t)(((l & 7) ^ (l >> 3)) << 4);

  const int aRowBase = (wr*64 + lr) * 64;
  const int bRowBase = (wc*32 + lr) * 64;
  int csw[2];
  csw[0] = ((lk     ) ^ (lr & 7)) << 3;
  csw[1] = ((lk + 4) ^ (lr & 7)) << 3;

  f32x4 acc[8][4];
  #pragma unroll
  for (int i = 0; i < 8; ++i)
    #pragma unroll
    for (int j = 0; j < 4; ++j){ acc[i][j][0]=0.f; acc[i][j][1]=0.f; acc[i][j][2]=0.f; acc[i][j][3]=0.f; }

  STG_A(0, 0, 0); STG_B(0, 0, 0); STG_A(0, 1, 0); STG_B(0, 1, 0);
  STG_A(1, 0, 1); STG_B(1, 0, 1); STG_A(1, 1, 1); STG_B(1, 1, 1);
  asm volatile("s_waitcnt vmcnt(8)" ::: "memory");
  BAR();
  bf16x8 a0c[2][4], b0c[2][2], a1f[2][4], b1f[2][2];
  RD_A(a0c, 0, 0); RD_B(b0c, 0, 0);

  for (int t = 0; t < 64; ++t){
    const int P = t & 1;
    RD_A(a1f, P, 1);
    BAR();
    mfma_quad<0,0>(acc, a0c, b0c);
    BAR();
    if (t < 62){ STG_A(P, 0, t+2); STG_B(P, 0, t+2); }
    RD_B(b1f, P, 1);
    BAR();
    mfma_quad<4,0>(acc, a1f, b0c);
    BAR();
    if (t < 62){
      STG_A(P, 1, t+2);
      asm volatile("s_waitcnt vmcnt(6)" ::: "memory");
    } else if (t == 62){
      asm volatile("s_waitcnt vmcnt(0)" ::: "memory");
    }
    BAR();
    mfma_quad<4,2>(acc, a1f, b1f);
    BAR();
    if (t < 62){ STG_B(P, 1, t+2); }
    BAR();
    mfma_quad<0,2>(acc, a0c, b1f);
    if (t < 63){ RD_A(a0c, P^1, 0); RD_B(b0c, P^1, 0); }
    BAR();
  }

  #pragma unroll
  for (int mh = 0; mh < 2; ++mh)
    #pragma unroll
    for (int m = 0; m < 4; ++m)
      #pragma unroll
      for (int nh = 0; nh < 2; ++nh)
        #pragma unroll
        for (int n = 0; n < 2; ++n)
          #pragma unroll
          for (int j = 0; j < 4; ++j){
            size_t gr = arow0 + mh*128 + wr*64 + m*16 + lk*4 + j;
            size_t gc = brow0 + nh*128 + wc*32 + n*16 + lr;
            float v = acc[mh*4+m][nh*2+n][j];
            if (OUTF32) ((float*)C)[gr * Nn + gc] = v;
            else        ((u16*)C)[gr * Nn + gc] = f2bf(v);
          }
}

// ============ gemm192 (R8 proven, 45% MfmaUtil): BM=256, BN=192, BK=64, rolled ============
#define STG_B3(PB, KT) do{ \
  _Pragma("unroll") for (int r2 = 0; r2 < 3; ++r2) \
    gload_lds16(Bg + bsrc3[r2] + (size_t)(KT)*128, \
                (char*)smem + 65536 + (PB)*24576 + r2*8192 + w*1024); }while(0)

#define RD_B0(DST, PP) do{ \
  _Pragma("unroll") for (int ks = 0; ks < 2; ++ks) \
  _Pragma("unroll") for (int n = 0; n < 2; ++n) \
    DST[ks][n] = *(const bf16x8*)&smem[32768 + (PP)*12288 + bRowBase + n*1024 + csw[ks]]; }while(0)
#define RD_B1(DST, PP) do{ \
  _Pragma("unroll") for (int ks = 0; ks < 2; ++ks) \
    DST[ks] = *(const bf16x8*)&smem[32768 + (PP)*12288 + bRowBase + 2048 + csw[ks]]; }while(0)

__device__ __forceinline__ void mfma_pair16(f32x4 (&acc)[8][3], int MO,
                                            const bf16x8 (&af)[2][4], const bf16x8 (&bf)[2][2]){
  __builtin_amdgcn_s_setprio(1);
  #pragma unroll
  for (int ks = 0; ks < 2; ++ks)
    #pragma unroll
    for (int m = 0; m < 4; ++m)
      #pragma unroll
      for (int n = 0; n < 2; ++n)
        acc[MO+m][n] = __builtin_amdgcn_mfma_f32_16x16x32_bf16(af[ks][m], bf[ks][n], acc[MO+m][n], 0, 0, 0);
  __builtin_amdgcn_s_setprio(0);
}
__device__ __forceinline__ void mfma_pair8(f32x4 (&acc)[8][3], int MO,
                                           const bf16x8 (&af)[2][4], const bf16x8 (&bf)[2]){
  __builtin_amdgcn_s_setprio(1);
  #pragma unroll
  for (int ks = 0; ks < 2; ++ks)
    #pragma unroll
    for (int m = 0; m < 4; ++m)
      acc[MO+m][2] = __builtin_amdgcn_mfma_f32_16x16x32_bf16(af[ks][m], bf[ks], acc[MO+m][2], 0, 0, 0);
  __builtin_amdgcn_s_setprio(0);
}

__global__ __launch_bounds__(512, 2) void gemm192(const u16* __restrict__ A, const u16* __restrict__ Bt,
                                                  u16* __restrict__ C, int Nn, int mt){
  __shared__ __align__(16) u16 smem[57344];   // 112 KB
  const int tid = threadIdx.x;
  const int l = tid & 63, w = tid >> 6;
  const int lr = l & 15, lk = l >> 4;
  const int wr = w >> 2, wc = w & 3;

  const int nwg = gridDim.x;
  const int sbid = ((int)blockIdx.x & 7) * (nwg >> 3) + ((int)blockIdx.x >> 3);
  const int bx = sbid % mt, by = sbid / mt;
  const size_t arow0 = (size_t)bx * 256;
  const size_t bcol0 = (size_t)by * 192;
  const char* Ag = (const char*)(A + arow0 * 4096);
  const char* Bg = (const char*)(Bt + bcol0 * 4096);

  const size_t off0 = (size_t)(w * 8 + (l >> 3)) * 8192 + (size_t)(((l & 7) ^ (l >> 3)) << 4);
  size_t bsrc3[3];
  #pragma unroll
  for (int r2 = 0; r2 < 3; ++r2){
    int idx = r2 * 512 + tid;
    int row = idx >> 3, ch = idx & 7;
    bsrc3[r2] = (size_t)row * 8192 + (size_t)((ch ^ (row & 7)) << 4);
  }

  const int aRowBase = (wr*64 + lr) * 64;
  const int bRowBase = (wc*48 + lr) * 64;
  int csw[2];
  csw[0] = ((lk     ) ^ (lr & 7)) << 3;
  csw[1] = ((lk + 4) ^ (lr & 7)) << 3;

  f32x4 acc[8][3];
  #pragma unroll
  for (int i = 0; i < 8; ++i)
    #pragma unroll
    for (int j = 0; j < 3; ++j){ acc[i][j][0]=0.f; acc[i][j][1]=0.f; acc[i][j][2]=0.f; acc[i][j][3]=0.f; }

  STG_A(0, 0, 0); STG_A(0, 1, 0); STG_B3(0, 0);
  STG_A(1, 0, 1); STG_A(1, 1, 1); STG_B3(1, 1);
  asm volatile("s_waitcnt vmcnt(7)" ::: "memory");
  BAR();
  bf16x8 a0c[2][4], a1f[2][4], b0c[2][2], b1f[2];
  RD_A(a0c, 0, 0); RD_B0(b0c, 0);

  for (int t = 0; t < 64; ++t){
    const int P = t & 1;
    RD_A(a1f, P, 1);
    BAR();
    mfma_pair16(acc, 0, a0c, b0c);
    BAR();
    if (t < 62){ STG_A(P, 0, t+2); }
    RD_B1(b1f, P);
    BAR();
    mfma_pair16(acc, 4, a1f, b0c);
    BAR();
    if (t < 62){
      STG_A(P, 1, t+2);
      asm volatile("s_waitcnt vmcnt(4)" ::: "memory");
    } else if (t == 62){
      asm volatile("s_waitcnt vmcnt(0)" ::: "memory");
    }
    BAR();
    mfma_pair8(acc, 4, a1f, b1f);
    BAR();
    if (t < 62){ STG_B3(P, t+2); }
    BAR();
    mfma_pair8(acc, 0, a0c, b1f);
    if (t < 63){ RD_A(a0c, P^1, 0); RD_B0(b0c, P^1); }
    BAR();
  }

  #pragma unroll
  for (int mh = 0; mh < 2; ++mh)
    #pragma unroll
    for (int m = 0; m < 4; ++m)
      #pragma unroll
      for (int f = 0; f < 3; ++f)
        #pragma unroll
        for (int j = 0; j < 4; ++j){
          size_t gr = arow0 + mh*128 + wr*64 + m*16 + lk*4 + j;
          size_t gc = bcol0 + wc*48 + f*16 + lr;
          C[gr * Nn + gc] = f2bf(acc[mh*4+m][f][j]);
        }
}

// ---------------- flash attention: 8 waves x 32 q-rows, KVBLK=64, 32x32x16 MFMA ----------------
// fused Q-RoPE, defer-max (T13), CU-pair-balanced qb order, setprio (T5), s1 diagonal skip.
__global__ __launch_bounds__(512, 2) void attn_k(const u16* __restrict__ QKV,
                                                 const u16* __restrict__ Vtg,
                                                 const int* __restrict__ pos,
                                                 u16* __restrict__ ctx){
  __shared__ __align__(16) u16 smem[32768];   // 64 KB
  const int tid = threadIdx.x;
  const int l = tid & 63, w = tid >> 6;
  const int lane31 = l & 31, hi = l >> 5;
  const int hb = blockIdx.x;
  const int b = hb >> 5, h = hb & 31, kvh = h >> 2;
  const int y = blockIdx.y;
  const int qb = (y < 4) ? (7 - y) : (y - 4);   // pairs (7,0),(6,1),(5,2),(4,3) co-resident
  const int q0w = qb * 256 + w * 32;
  const int qg = q0w + lane31;

  const u16* Qp = QKV + (size_t)b * S_ * QSTR + (size_t)h * D_;
  const char* Kp = (const char*)(QKV + (size_t)b * S_ * QSTR + 4096 + (size_t)kvh * D_);
  const char* Vp = (const char*)(Vtg + ((size_t)b * 1024 + kvh * 128) * S_);

  bf16x8 qf[8];
  #pragma unroll
  for (int dt = 0; dt < 8; ++dt)
    qf[dt] = *(const bf16x8*)(Qp + (size_t)qg * QSTR + dt * 16 + hi * 8);

  // fused Q-RoPE
  {
    float fp = (float)pos[b * S_ + qg];
    #pragma unroll
    for (int dt = 0; dt < 4; ++dt){
      bf16x8 lo = qf[dt], hi8 = qf[dt + 4], nlo, nhi;
      #pragma unroll
      for (int j = 0; j < 8; ++j){
        int d = dt * 16 + hi * 8 + j;
        float invf = exp2f(-(float)(2 * d) * (13.287712379549449f / 128.0f));
        float f = fp * invf;
        float sv = __sinf(f), cv = __cosf(f);
        float x1 = bf2f((u16)lo[j]), x2 = bf2f((u16)hi8[j]);
        nlo[j] = (short)f2bf(x1 * cv - x2 * sv);
        nhi[j] = (short)f2bf(x2 * cv + x1 * sv);
      }
      qf[dt] = nlo; qf[dt + 4] = nhi;
    }
  }

  const int krow0 = (2*w)*4 + (l >> 4), krow1 = krow0 + 4;
  const size_t koff0 = (size_t)krow0 * (QSTR*2) + (((l & 15) << 4) ^ ((krow0 & 7) << 4));
  const size_t koff1 = (size_t)krow1 * (QSTR*2) + (((l & 15) << 4) ^ ((krow1 & 7) << 4));
  const int vrow0 = (2*w)*8 + (l >> 3), vrow1 = vrow0 + 8;
  const size_t voff0 = (size_t)vrow0 * (S_*2) + (((l & 7) << 4) ^ ((vrow0 & 7) << 4));
  const size_t voff1 = (size_t)vrow1 * (S_*2) + (((l & 7) << 4) ^ ((vrow1 & 7) << 4));

  f32x16 acc[4];
  #pragma unroll
  for (int dt = 0; dt < 4; ++dt)
    #pragma unroll
    for (int i = 0; i < 16; ++i) acc[dt][i] = 0.f;
  float mrow = -3e38f, lsum = 0.f;

  const int nt = qb * 4 + 4;

  auto STAGE = [&](int t, int bufn){
    char* Kb = (char*)smem + bufn * 16384;
    char* Vb = (char*)smem + 32768 + bufn * 16384;
    size_t kb = (size_t)t * 64 * (QSTR*2);
    size_t vb = (size_t)t * 128;
    gload_lds16(Kp + kb + koff0, Kb + (2*w)*1024);
    gload_lds16(Kp + kb + koff1, Kb + (2*w+1)*1024);
    gload_lds16(Vp + vb + voff0, Vb + (2*w)*1024);
    gload_lds16(Vp + vb + voff1, Vb + (2*w+1)*1024);
  };

  STAGE(0, 0);
  __syncthreads();
  int buf = 0;
  for (int t = 0; t < nt; ++t){
    if (t + 1 < nt) STAGE(t + 1, buf ^ 1);
    const int kbase = t * 64;
    if (kbase <= q0w + 31){
      const char* Kb = (const char*)smem + buf * 16384;
      const char* Vb = (const char*)smem + 32768 + buf * 16384;
      const int swz = (lane31 & 7) << 4;

      f32x16 s0, s1;
      #pragma unroll
      for (int i = 0; i < 16; ++i){ s0[i] = 0.f; s1[i] = 0.f; }
      const bool doS1 = (kbase + 32 <= q0w + 31);
      __builtin_amdgcn_s_setprio(1);
      #pragma unroll
      for (int dt = 0; dt < 8; ++dt){
        bf16x8 kf = *(const bf16x8*)(Kb + lane31*256 + ((dt*32 + hi*16) ^ swz));
        s0 = __builtin_amdgcn_mfma_f32_32x32x16_bf16(kf, qf[dt], s0, 0, 0, 0);
      }
      if (doS1){
        #pragma unroll
        for (int dt = 0; dt < 8; ++dt){
          bf16x8 kf = *(const bf16x8*)(Kb + (32 + lane31)*256 + ((dt*32 + hi*16) ^ swz));
          s1 = __builtin_amdgcn_mfma_f32_32x32x16_bf16(kf, qf[dt], s1, 0, 0, 0);
        }
      }
      __builtin_amdgcn_s_setprio(0);

      if (kbase + 63 > q0w){
        int thr = qg - kbase;
        #pragma unroll
        for (int r = 0; r < 16; ++r){
          int kc = (r & 3) + 8*(r >> 2) + 4*hi;
          s0[r] = (kc > thr)      ? -1e30f : s0[r];
          s1[r] = (kc + 32 > thr) ? -1e30f : s1[r];
        }
      }

      float tmax = s0[0];
      #pragma unroll
      for (int r = 1; r < 16; ++r) tmax = fmaxf(tmax, s0[r]);
      #pragma unroll
      for (int r = 0; r < 16; ++r) tmax = fmaxf(tmax, s1[r]);
      tmax = fmaxf(tmax, __shfl_xor(tmax, 32));
      if (!__all(tmax - mrow <= 62.7f)){
        float mn = fmaxf(mrow, tmax);
        float rf = exp2f((mrow - mn) * KSC);
        mrow = mn;
        lsum *= rf;
        #pragma unroll
        for (int dt = 0; dt < 4; ++dt)
          #pragma unroll
          for (int i = 0; i < 16; ++i) acc[dt][i] *= rf;
      }
      float ps = 0.f;
      #pragma unroll
      for (int r = 0; r < 16; ++r){
        float a = exp2f((s0[r] - mrow) * KSC);
        float c = exp2f((s1[r] - mrow) * KSC);
        s0[r] = a; s1[r] = c; ps += a + c;
      }
      ps += __shfl_xor(ps, 32);
      lsum += ps;

      u32 pw[16];
      #pragma unroll
      for (int g = 0; g < 4; ++g){
        pw[2*g]     = (u32)f2bf(s0[4*g])   | ((u32)f2bf(s0[4*g+1]) << 16);
        pw[2*g+1]   = (u32)f2bf(s0[4*g+2]) | ((u32)f2bf(s0[4*g+3]) << 16);
        pw[8+2*g]   = (u32)f2bf(s1[4*g])   | ((u32)f2bf(s1[4*g+1]) << 16);
        pw[8+2*g+1] = (u32)f2bf(s1[4*g+2]) | ((u32)f2bf(s1[4*g+3]) << 16);
      }

      #pragma unroll
      for (int kt = 0; kt < 4; ++kt){
        u32 W0 = pw[kt*4+0], W1 = pw[kt*4+1], W2 = pw[kt*4+2], W3 = pw[kt*4+3];
        u32 x0 = hi ? W0 : W2;
        u32 x1 = hi ? W1 : W3;
        u32 y0 = __shfl_xor(x0, 32);
        u32 y1 = __shfl_xor(x1, 32);
        u32 w0 = hi ? y0 : W0;
        u32 w1 = hi ? y1 : W1;
        u32 w2 = hi ? W2 : y0;
        u32 w3 = hi ? W3 : y1;
        u32x4 pk; pk[0]=w0; pk[1]=w1; pk[2]=w2; pk[3]=w3;
        bf16x8 pa = __builtin_bit_cast(bf16x8, pk);
        __builtin_amdgcn_s_setprio(1);
        #pragma unroll
        for (int dt = 0; dt < 4; ++dt){
          bf16x8 vf = *(const bf16x8*)(Vb + (dt*32 + lane31)*128 + ((kt*32 + hi*16) ^ swz));
          acc[dt] = __builtin_amdgcn_mfma_f32_32x32x16_bf16(vf, pa, acc[dt], 0, 0, 0);
        }
        __builtin_amdgcn_s_setprio(0);
      }
    }
    __syncthreads();
    buf ^= 1;
  }

  __syncthreads();
  u16* Ot = smem + w * 4096;
  float inv = 1.f / lsum;
  #pragma unroll
  for (int dt = 0; dt < 4; ++dt)
    #pragma unroll
    for (int r = 0; r < 16; ++r){
      int d = dt*32 + (r & 3) + 8*(r >> 2) + 4*hi;
      Ot[lane31*128 + (d ^ ((lane31 & 15) << 2))] = f2bf(acc[dt][r] * inv);
    }
  u16* outp = ctx + ((size_t)(b * S_ + q0w)) * HID_ + h * D_;
  #pragma unroll
  for (int it = 0; it < 16; ++it){
    int id = it * 64 + l;
    int q = id >> 5;
    int c4 = (id & 31) * 4;
    ushort4 vv = *(const ushort4*)(Ot + q*128 + (c4 ^ ((q & 15) << 2)));
    *(ushort4*)(outp + (size_t)q * HID_ + c4) = vv;
  }
}

extern "C" void kernel_launch(void* const* d_in, const int* in_sizes, int n_in,
                              void* d_out, int out_size, void* d_ws, size_t ws_size,
                              hipStream_t stream) {
  const float* x  = (const float*)d_in[0];
  const int*   pos = (const int*)d_in[2];
  const float* Wq = (const float*)d_in[3];
  const float* Wk = (const float*)d_in[4];
  const float* Wv = (const float*)d_in[5];
  const float* Wo = (const float*)d_in[6];

  char* ws = (char*)d_ws;
  u16* xb   = (u16*)(ws);                               // 32MB; reused as ctx after QKV
  u16* WT   = (u16*)(ws + ((size_t)32 << 20));          // 48MB: Wq^T|Wk^T|Wv^T (dead after QKV gemm)
  u16* WoT  = (u16*)(ws + ((size_t)80 << 20));          // 32MB
  u16* QKVb = (u16*)(ws + ((size_t)112 << 20));         // 48MB: [4096][6144]
  u16* Vtg  = (u16*)(ws + ((size_t)32 << 20));          // 8MB overlay on WT: [b*1024+vd][S]

  prep<<<12288, 256, 0, stream>>>(x, xb, Wq, Wk, Wv, Wo, WT, WoT);
  gemm192<<<512, 512, 0, stream>>>(xb, WT, QKVb, 6144, 16);
  rope_vtrans<<<9216, 256, 0, stream>>>(QKVb, Vtg, pos);
  attn_k<<<dim3(64, 8), 512, 0, stream>>>(QKVb, Vtg, pos, xb);
  gemm256<true><<<256, 512, 0, stream>>>(xb, WoT, d_out, 4096, 16);
}